// Round 7
// baseline (3533.854 us; speedup 1.0000x reference)
//
#include <hip/hip_runtime.h>

#define T_STEPS 12
#define NN 100000
#define EE 3200000
#define HD 64
#define OD 32
#define NBK 391  // (NN+255)/256 buckets of 256 nodes

typedef __attribute__((ext_vector_type(8))) short short8;
typedef __attribute__((ext_vector_type(4))) float f32x4;
typedef __attribute__((ext_vector_type(2))) float f32x2;
typedef unsigned short u16;
typedef unsigned char u8;

__device__ __forceinline__ u16 f2b(float x) {
  union { float f; unsigned u; } v; v.f = x;
  unsigned r = v.u + 0x7FFFu + ((v.u >> 16) & 1u);
  return (u16)(r >> 16);
}
__device__ __forceinline__ float sigm(float x) {
  x = fminf(fmaxf(x, -30.f), 30.f);
  return 1.0f / (1.0f + __expf(-x));
}
__device__ __forceinline__ float tanh_f(float x) {
  x = fminf(fmaxf(x, -15.f), 15.f);
  float e = __expf(2.0f * x);
  return (e - 1.0f) / (e + 1.0f);
}

// fp8 e4m3 (OCP) helpers via gfx950 HW converts
__device__ __forceinline__ uint2 pack8_fp8(const float* f) {
  unsigned lo = 0, hi = 0;
  lo = __builtin_amdgcn_cvt_pk_fp8_f32(f[0], f[1], lo, false);
  lo = __builtin_amdgcn_cvt_pk_fp8_f32(f[2], f[3], lo, true);
  hi = __builtin_amdgcn_cvt_pk_fp8_f32(f[4], f[5], hi, false);
  hi = __builtin_amdgcn_cvt_pk_fp8_f32(f[6], f[7], hi, true);
  return make_uint2(lo, hi);
}
__device__ __forceinline__ u8 f2q(float x) {
  return (u8)(__builtin_amdgcn_cvt_pk_fp8_f32(x, 0.f, 0u, false) & 0xFFu);
}
// 16 fp8 -> 8 x f32x2 accumulate (v_pk_add_f32 path)
__device__ __forceinline__ void dec16_acc2(uint4 q, f32x2* a) {
  a[0] += __builtin_amdgcn_cvt_pk_f32_fp8(q.x, false);
  a[1] += __builtin_amdgcn_cvt_pk_f32_fp8(q.x, true);
  a[2] += __builtin_amdgcn_cvt_pk_f32_fp8(q.y, false);
  a[3] += __builtin_amdgcn_cvt_pk_f32_fp8(q.y, true);
  a[4] += __builtin_amdgcn_cvt_pk_f32_fp8(q.z, false);
  a[5] += __builtin_amdgcn_cvt_pk_f32_fp8(q.z, true);
  a[6] += __builtin_amdgcn_cvt_pk_f32_fp8(q.w, false);
  a[7] += __builtin_amdgcn_cvt_pk_f32_fp8(q.w, true);
}
__device__ __forceinline__ short8 s8_from_fp8(uint2 q) {
  f32x2 p0 = __builtin_amdgcn_cvt_pk_f32_fp8(q.x, false);
  f32x2 p1 = __builtin_amdgcn_cvt_pk_f32_fp8(q.x, true);
  f32x2 p2 = __builtin_amdgcn_cvt_pk_f32_fp8(q.y, false);
  f32x2 p3 = __builtin_amdgcn_cvt_pk_f32_fp8(q.y, true);
  short8 o;
  o[0] = (short)f2b(p0[0]); o[1] = (short)f2b(p0[1]);
  o[2] = (short)f2b(p1[0]); o[3] = (short)f2b(p1[1]);
  o[4] = (short)f2b(p2[0]); o[5] = (short)f2b(p2[1]);
  o[6] = (short)f2b(p3[0]); o[7] = (short)f2b(p3[1]);
  return o;
}
__device__ __forceinline__ short8 s8_from_f32(float4 a, float4 b) {
  short8 o;
  o[0] = (short)f2b(a.x); o[1] = (short)f2b(a.y);
  o[2] = (short)f2b(a.z); o[3] = (short)f2b(a.w);
  o[4] = (short)f2b(b.x); o[5] = (short)f2b(b.y);
  o[6] = (short)f2b(b.z); o[7] = (short)f2b(b.w);
  return o;
}

// ================= bucketed CSR build =================
__global__ __launch_bounds__(256) void k_bhist(const int* __restrict__ dst,
                                               int* __restrict__ bcnt, int E) {
  __shared__ int h[NBK];
  for (int i = threadIdx.x; i < NBK; i += 256) h[i] = 0;
  __syncthreads();
  int base = blockIdx.x * 4096;
#pragma unroll
  for (int i = 0; i < 16; ++i) {
    int e = base + i * 256 + threadIdx.x;
    if (e < E) atomicAdd(&h[dst[e] >> 8], 1);
  }
  __syncthreads();
  for (int i = threadIdx.x; i < NBK; i += 256)
    if (h[i]) atomicAdd(&bcnt[i], h[i]);
}

__global__ __launch_bounds__(512) void k_bscan(const int* __restrict__ bcnt,
                                               int* __restrict__ bcur) {
  __shared__ int buf[512];
  int tid = threadIdx.x;
  int v = (tid < NBK) ? bcnt[tid] : 0;
  buf[tid] = v;
  __syncthreads();
  for (int off = 1; off < 512; off <<= 1) {
    int t = (tid >= off) ? buf[tid - off] : 0;
    __syncthreads();
    buf[tid] += t;
    __syncthreads();
  }
  if (tid < NBK) bcur[tid] = buf[tid] - v;
}

__global__ __launch_bounds__(256) void k_bscatter(const int* __restrict__ src,
                                                  const int* __restrict__ dst,
                                                  int* __restrict__ bcur,
                                                  uint2* __restrict__ binned, int E) {
  __shared__ int h[NBK];
  __shared__ int base[NBK];
  __shared__ int cur[NBK];
  for (int i = threadIdx.x; i < NBK; i += 256) { h[i] = 0; cur[i] = 0; }
  __syncthreads();
  int b0 = blockIdx.x * 4096;
  int d[16], s[16];
#pragma unroll
  for (int i = 0; i < 16; ++i) {
    int e = b0 + i * 256 + threadIdx.x;
    if (e < E) {
      d[i] = dst[e];
      s[i] = src[e];
      atomicAdd(&h[d[i] >> 8], 1);
    } else d[i] = -1;
  }
  __syncthreads();
  for (int i = threadIdx.x; i < NBK; i += 256)
    if (h[i]) base[i] = atomicAdd(&bcur[i], h[i]);
  __syncthreads();
#pragma unroll
  for (int i = 0; i < 16; ++i) {
    if (d[i] >= 0) {
      int bk = d[i] >> 8;
      int r = atomicAdd(&cur[bk], 1);
      binned[base[bk] + r] = make_uint2((unsigned)s[i], (unsigned)d[i]);
    }
  }
}

__global__ __launch_bounds__(256) void k_count2(const uint2* __restrict__ binned,
                                                int* __restrict__ deg, int E) {
  int e = blockIdx.x * 256 + threadIdx.x;
  if (e < E) atomicAdd(&deg[binned[e].y], 1);
}

__global__ __launch_bounds__(1024) void k_scanA(const int* __restrict__ deg,
                                                int* __restrict__ excl,
                                                int* __restrict__ btot, int n) {
  __shared__ int buf[1024];
  int tid = threadIdx.x;
  int i = blockIdx.x * 1024 + tid;
  int v = (i < n) ? deg[i] : 0;
  buf[tid] = v;
  __syncthreads();
  for (int off = 1; off < 1024; off <<= 1) {
    int t = (tid >= off) ? buf[tid - off] : 0;
    __syncthreads();
    buf[tid] += t;
    __syncthreads();
  }
  if (i < n) excl[i] = buf[tid] - v;
  if (tid == 1023) btot[blockIdx.x] = buf[1023];
}

__global__ __launch_bounds__(128) void k_scanB(const int* __restrict__ btot,
                                               int* __restrict__ boffs, int nb) {
  __shared__ int buf[128];
  int tid = threadIdx.x;
  int v = (tid < nb) ? btot[tid] : 0;
  buf[tid] = v;
  __syncthreads();
  for (int off = 1; off < 128; off <<= 1) {
    int t = (tid >= off) ? buf[tid - off] : 0;
    __syncthreads();
    buf[tid] += t;
    __syncthreads();
  }
  if (tid < nb) boffs[tid] = buf[tid] - v;
}

__global__ __launch_bounds__(1024) void k_scanC(const int* __restrict__ deg,
                                                const int* __restrict__ excl,
                                                const int* __restrict__ boffs,
                                                int* __restrict__ row_ptr,
                                                int* __restrict__ cursor,
                                                float* __restrict__ deg_inv, int n) {
  int i = blockIdx.x * 1024 + threadIdx.x;
  if (i < n) {
    int v = excl[i] + boffs[blockIdx.x];
    int d = deg[i];
    row_ptr[i] = v;
    cursor[i] = v;
    deg_inv[i] = d ? (1.0f / (float)d) : 0.0f;
    if (i == n - 1) row_ptr[n] = v + d;
  }
}

__global__ __launch_bounds__(256) void k_scatter2(const uint2* __restrict__ binned,
                                                  int* __restrict__ cursor,
                                                  int* __restrict__ csr, int E) {
  int e = blockIdx.x * 256 + threadIdx.x;
  if (e < E) {
    uint2 p = binned[e];
    int pos = atomicAdd(&cursor[p.y], 1);
    csr[pos] = (int)p.x;
  }
}

// ---------------- weight prep: fragment-ordered bf16 B ----------------
__global__ __launch_bounds__(256) void k_prep(const float* __restrict__ Wxs,
                                              const float* __restrict__ Wxn,
                                              const float* __restrict__ Whs,
                                              const float* __restrict__ Whn,
                                              u16* __restrict__ bprep) {
  int idx = blockIdx.x * 256 + threadIdx.x;  // 0..131071
  int l = idx >> 16;
  int kb = (idx >> 13) & 7;
  int fi = (idx >> 9) & 15;
  int ln = (idx >> 3) & 63;
  int j = idx & 7;
  int fc = kb * 32 + ((ln >> 4) << 3) + j;
  int g = fi & 3;
  int kk = ((fi >> 2) << 4) + (ln & 15);
  int t = fc >> 6, f = fc & 63;
  const float* tabs[4] = {Wxs, Wxn, Whs, Whn};
  bprep[idx] = f2b(tabs[t][((size_t)(l * 4 + g) * 64 + f) * 64 + kk]);
}

__global__ __launch_bounds__(256) void k_prepw(const float* __restrict__ Wout,
                                               u16* __restrict__ wp) {
  int idx = blockIdx.x * 256 + threadIdx.x;  // 0..2047
  int kb = idx >> 10;
  int fi = (idx >> 9) & 1;
  int ln = (idx >> 3) & 63;
  int j = idx & 7;
  int k = kb * 32 + ((ln >> 4) << 3) + j;
  int o = fi * 16 + (ln & 15);
  wp[idx] = f2b(Wout[k * 32 + o]);
}

// ---------------- batch x -> transposed fp8 XQ[N][T*64] ----------------
__global__ __launch_bounds__(256) void k_convxall(const float* __restrict__ x,
                                                  u8* __restrict__ XQ) {
  int tid = blockIdx.x * 256 + threadIdx.x;  // (t*NN + n)*8 + j
  int j = tid & 7;
  int tn = tid >> 3;
  int n = tn % NN;
  int t = tn / NN;
  const float* rp = x + (size_t)tn * 64 + j * 8;
  float4 v0 = *reinterpret_cast<const float4*>(rp);
  float4 v1 = *reinterpret_cast<const float4*>(rp + 4);
  float f[8] = {v0.x, v0.y, v0.z, v0.w, v1.x, v1.y, v1.z, v1.w};
  *reinterpret_cast<uint2*>(XQ + (size_t)n * 768 + t * 64 + j * 8) = pack8_fp8(f);
}

// ---------------- init h (both layers) -> bf16 tables + fp8 HQ pair ---------
__global__ __launch_bounds__(256) void k_inith(const float* __restrict__ h0,
                                               u16* __restrict__ H0bf,
                                               u16* __restrict__ L1bf,
                                               u8* __restrict__ HQ) {
  int idx = blockIdx.x * 256 + threadIdx.x;  // N*8
  int n = idx >> 3, j = idx & 7;
#pragma unroll
  for (int L = 0; L < 2; ++L) {
    const float* rp = h0 + (size_t)L * NN * 64 + (size_t)n * 64 + j * 8;
    float4 v0 = *reinterpret_cast<const float4*>(rp);
    float4 v1 = *reinterpret_cast<const float4*>(rp + 4);
    float f[8] = {v0.x, v0.y, v0.z, v0.w, v1.x, v1.y, v1.z, v1.w};
    short8 o;
#pragma unroll
    for (int i = 0; i < 8; ++i) o[i] = (short)f2b(f[i]);
    if (L == 0)
      *reinterpret_cast<short8*>(H0bf + (size_t)n * 64 + j * 8) = o;
    else
      *reinterpret_cast<short8*>(L1bf + (size_t)n * 64 + j * 8) = o;
    *reinterpret_cast<uint2*>(HQ + (size_t)n * 128 + L * 64 + j * 8) = pack8_fp8(f);
  }
}

// ---------------- batched x aggregation: all T steps in one pass ------------
// 4 edge slots (g) x 16 lanes (m); per edge 3 passes of 16B/lane.
__global__ __launch_bounds__(256) void k_aggx(const u8* __restrict__ XQ,
                                              const int* __restrict__ row_ptr,
                                              const int* __restrict__ csr,
                                              const float* __restrict__ deg_inv,
                                              u8* __restrict__ AGGXq) {
  int node = blockIdx.x * 4 + (threadIdx.x >> 6);
  int lane = threadIdx.x & 63;
  int g = lane >> 4, m = lane & 15;
  int start = row_ptr[node], end = row_ptr[node + 1];
  f32x2 acc[3][8];
#pragma unroll
  for (int p = 0; p < 3; ++p)
#pragma unroll
    for (int i = 0; i < 8; ++i) acc[p][i] = (f32x2){0.f, 0.f};
  int e = start + g;
  for (; e + 4 < end; e += 8) {
    int s0 = csr[e], s1 = csr[e + 4];
    const u8* r0 = XQ + (size_t)s0 * 768 + m * 16;
    const u8* r1 = XQ + (size_t)s1 * 768 + m * 16;
#pragma unroll
    for (int p = 0; p < 3; ++p) {
      uint4 q0 = *reinterpret_cast<const uint4*>(r0 + p * 256);
      uint4 q1 = *reinterpret_cast<const uint4*>(r1 + p * 256);
      dec16_acc2(q0, acc[p]);
      dec16_acc2(q1, acc[p]);
    }
  }
  if (e < end) {
    int s0 = csr[e];
    const u8* r0 = XQ + (size_t)s0 * 768 + m * 16;
#pragma unroll
    for (int p = 0; p < 3; ++p) {
      uint4 q0 = *reinterpret_cast<const uint4*>(r0 + p * 256);
      dec16_acc2(q0, acc[p]);
    }
  }
#pragma unroll
  for (int off = 16; off < 64; off <<= 1)
#pragma unroll
    for (int p = 0; p < 3; ++p)
#pragma unroll
      for (int i = 0; i < 8; ++i) {
        acc[p][i][0] += __shfl_xor(acc[p][i][0], off);
        acc[p][i][1] += __shfl_xor(acc[p][i][1], off);
      }
  if (g == 0) {
    float sc = deg_inv[node];
#pragma unroll
    for (int p = 0; p < 3; ++p) {
      float f[16];
#pragma unroll
      for (int i = 0; i < 8; ++i) {
        f[i * 2] = acc[p][i][0] * sc;
        f[i * 2 + 1] = acc[p][i][1] * sc;
      }
      uint4 o;
      unsigned w;
      w = 0; w = __builtin_amdgcn_cvt_pk_fp8_f32(f[0], f[1], w, false);
      w = __builtin_amdgcn_cvt_pk_fp8_f32(f[2], f[3], w, true); o.x = w;
      w = 0; w = __builtin_amdgcn_cvt_pk_fp8_f32(f[4], f[5], w, false);
      w = __builtin_amdgcn_cvt_pk_fp8_f32(f[6], f[7], w, true); o.y = w;
      w = 0; w = __builtin_amdgcn_cvt_pk_fp8_f32(f[8], f[9], w, false);
      w = __builtin_amdgcn_cvt_pk_fp8_f32(f[10], f[11], w, true); o.z = w;
      w = 0; w = __builtin_amdgcn_cvt_pk_fp8_f32(f[12], f[13], w, false);
      w = __builtin_amdgcn_cvt_pk_fp8_f32(f[14], f[15], w, true); o.w = w;
      int t = p * 4 + (m >> 2);
      *reinterpret_cast<uint4*>(AGGXq + ((size_t)t * NN + node) * 64 + (m & 3) * 16) = o;
    }
  }
}

// ---------------- dual mean aggregation over HQ [N][128] fp8 ----------------
// 8 edge slots x 8 lanes x 16B uint4; depth-4 main, depth-2/1 tail.
__global__ __launch_bounds__(256) void k_agg_pair(const u8* __restrict__ Q,
                                                  const int* __restrict__ row_ptr,
                                                  const int* __restrict__ csr,
                                                  const float* __restrict__ deg_inv,
                                                  u16* __restrict__ outp) {
  int node = blockIdx.x * 4 + (threadIdx.x >> 6);
  int lane = threadIdx.x & 63;
  int g = lane >> 3, m = lane & 7;
  int start = row_ptr[node], end = row_ptr[node + 1];
  f32x2 a[8];
#pragma unroll
  for (int i = 0; i < 8; ++i) a[i] = (f32x2){0.f, 0.f};
  int e = start + g;
  for (; e + 24 < end; e += 32) {
    int s0 = csr[e], s1 = csr[e + 8], s2 = csr[e + 16], s3 = csr[e + 24];
    uint4 q0 = *reinterpret_cast<const uint4*>(Q + (size_t)s0 * 128 + m * 16);
    uint4 q1 = *reinterpret_cast<const uint4*>(Q + (size_t)s1 * 128 + m * 16);
    uint4 q2 = *reinterpret_cast<const uint4*>(Q + (size_t)s2 * 128 + m * 16);
    uint4 q3 = *reinterpret_cast<const uint4*>(Q + (size_t)s3 * 128 + m * 16);
    dec16_acc2(q0, a); dec16_acc2(q1, a); dec16_acc2(q2, a); dec16_acc2(q3, a);
  }
  if (e + 8 < end) {
    int s0 = csr[e], s1 = csr[e + 8];
    uint4 q0 = *reinterpret_cast<const uint4*>(Q + (size_t)s0 * 128 + m * 16);
    uint4 q1 = *reinterpret_cast<const uint4*>(Q + (size_t)s1 * 128 + m * 16);
    dec16_acc2(q0, a); dec16_acc2(q1, a);
    e += 16;
  }
  if (e < end) {
    int s0 = csr[e];
    uint4 q0 = *reinterpret_cast<const uint4*>(Q + (size_t)s0 * 128 + m * 16);
    dec16_acc2(q0, a);
  }
#pragma unroll
  for (int off = 8; off < 64; off <<= 1)
#pragma unroll
    for (int i = 0; i < 8; ++i) {
      a[i][0] += __shfl_xor(a[i][0], off);
      a[i][1] += __shfl_xor(a[i][1], off);
    }
  if (g == 0) {
    float sc = deg_inv[node];
    short8 o0, o1;
#pragma unroll
    for (int i = 0; i < 4; ++i) {
      o0[i * 2] = (short)f2b(a[i][0] * sc);
      o0[i * 2 + 1] = (short)f2b(a[i][1] * sc);
      o1[i * 2] = (short)f2b(a[4 + i][0] * sc);
      o1[i * 2 + 1] = (short)f2b(a[4 + i][1] * sc);
    }
    *reinterpret_cast<short8*>(outp + (size_t)node * 128 + m * 16) = o0;
    *reinterpret_cast<short8*>(outp + (size_t)node * 128 + m * 16 + 8) = o1;
  }
}

// ---------------- layer-0 gates (standalone, step 0) ----------------
__global__ __launch_bounds__(256, 2) void k_gates0(
    const float* __restrict__ xin, const u8* __restrict__ aggxq,
    u16* __restrict__ h0bf, const u16* __restrict__ agghl,
    u8* __restrict__ hq, float* __restrict__ cst, float* __restrict__ hf32,
    const u16* __restrict__ bprepl,
    const float* __restrict__ wcl, const float* __restrict__ biasl,
    int n_nodes, int writef32) {
  const int tid = threadIdx.x;
  const int lane = tid & 63;
  const int w = tid >> 6;
  const int nb = blockIdx.x * 64;
  const int cl = lane & 15;
  const int kg = lane >> 4;

  short8 breg[8][4];
#pragma unroll
  for (int kb = 0; kb < 8; ++kb)
#pragma unroll
    for (int fl = 0; fl < 4; ++fl)
      breg[kb][fl] = *reinterpret_cast<const short8*>(
          bprepl + (kb << 13) + (((w << 2) + fl) << 9) + (lane << 3));

  int gnc[4];
#pragma unroll
  for (int rg = 0; rg < 4; ++rg) {
    int g = nb + rg * 16 + cl;
    gnc[rg] = (g < n_nodes) ? g : (n_nodes - 1);
  }

  f32x4 acc[4][4];
  f32x4 z4 = {0.f, 0.f, 0.f, 0.f};
#pragma unroll
  for (int a = 0; a < 4; ++a)
#pragma unroll
    for (int b = 0; b < 4; ++b) acc[a][b] = z4;

  const int koff = kg << 3;
#pragma unroll
  for (int kb = 0; kb < 8; ++kb) {
    const int idx = ((kb & 1) << 5) + koff;
#pragma unroll
    for (int rg = 0; rg < 4; ++rg) {
      short8 a;
      if (kb < 2) {
        const float* rp = xin + (size_t)gnc[rg] * 64 + idx;
        a = s8_from_f32(*reinterpret_cast<const float4*>(rp),
                        *reinterpret_cast<const float4*>(rp + 4));
      } else if (kb < 4) {
        a = s8_from_fp8(*reinterpret_cast<const uint2*>(aggxq + (size_t)gnc[rg] * 64 + idx));
      } else if (kb < 6) {
        a = *reinterpret_cast<const short8*>(h0bf + (size_t)gnc[rg] * 64 + idx);
      } else {
        a = *reinterpret_cast<const short8*>(agghl + (size_t)gnc[rg] * 128 + idx);
      }
      acc[rg][0] = __builtin_amdgcn_mfma_f32_16x16x32_bf16(a, breg[kb][0], acc[rg][0], 0, 0, 0);
      acc[rg][1] = __builtin_amdgcn_mfma_f32_16x16x32_bf16(a, breg[kb][1], acc[rg][1], 0, 0, 0);
      acc[rg][2] = __builtin_amdgcn_mfma_f32_16x16x32_bf16(a, breg[kb][2], acc[rg][2], 0, 0, 0);
      acc[rg][3] = __builtin_amdgcn_mfma_f32_16x16x32_bf16(a, breg[kb][3], acc[rg][3], 0, 0, 0);
    }
  }
  __syncthreads();  // all h0bf A-reads complete before in-place writes

  const int k = (w << 4) + cl;
  const float wci = wcl[k], wcf = wcl[64 + k], wco = wcl[128 + k];
  const float bi = biasl[k], bfg = biasl[64 + k], bc = biasl[128 + k], bo = biasl[192 + k];
#pragma unroll
  for (int rg = 0; rg < 4; ++rg) {
#pragma unroll
    for (int r = 0; r < 4; ++r) {
      int n = nb + rg * 16 + kg * 4 + r;
      if (n < n_nodes) {
        size_t off = (size_t)n * 64 + k;
        float c_old = cst[off];
        float ig = sigm(acc[rg][0][r] + wci * c_old + bi);
        float fg = sigm(acc[rg][1][r] + wcf * c_old + bfg);
        float ct = tanh_f(acc[rg][2][r] + bc);
        float nc = fg * c_old + ig * ct;
        float og = sigm(acc[rg][3][r] + wco * nc + bo);
        float nh = og * tanh_f(nc);
        cst[off] = nc;
        h0bf[off] = f2b(nh);
        hq[(size_t)n * 128 + k] = f2q(nh);
        if (writef32) hf32[off] = nh;
      }
    }
  }
}

// ------- fused: layer-1 gates (step t) + out-proj + layer-0 gates (step t+1)
__global__ __launch_bounds__(256, 2) void k_gates10(
    u16* __restrict__ h0bf, const u16* __restrict__ agghl,
    u16* __restrict__ l1bf, u8* __restrict__ hq,
    float* __restrict__ cst, float* __restrict__ hf32,
    const u16* __restrict__ bprep0, const u16* __restrict__ bprep1,
    const float* __restrict__ wc, const float* __restrict__ bias,
    const u16* __restrict__ wproj, const float* __restrict__ boutp,
    float* __restrict__ outp,
    const float* __restrict__ xnext, const u8* __restrict__ aggxqnext,
    int n_nodes, int do0, int wf0, int wf1) {
  __shared__ u16 Hsm[64 * 64];  // 8 KB
  const int tid = threadIdx.x;
  const int lane = tid & 63;
  const int w = tid >> 6;
  const int nb = blockIdx.x * 64;
  const int cl = lane & 15;
  const int kg = lane >> 4;
  const int koff = kg << 3;
  const int k = (w << 4) + cl;
  f32x4 z4 = {0.f, 0.f, 0.f, 0.f};

  int gnc[4];
#pragma unroll
  for (int rg = 0; rg < 4; ++rg) {
    int g = nb + rg * 16 + cl;
    gnc[rg] = (g < n_nodes) ? g : (n_nodes - 1);
  }

  // ================== part 1: layer-1 gates (step t) ==================
  {
    short8 breg[8][4];
#pragma unroll
    for (int kb = 0; kb < 8; ++kb)
#pragma unroll
      for (int fl = 0; fl < 4; ++fl)
        breg[kb][fl] = *reinterpret_cast<const short8*>(
            bprep1 + (kb << 13) + (((w << 2) + fl) << 9) + (lane << 3));

    f32x4 acc[4][4];
#pragma unroll
    for (int a = 0; a < 4; ++a)
#pragma unroll
      for (int b = 0; b < 4; ++b) acc[a][b] = z4;

#pragma unroll
    for (int kb = 0; kb < 8; ++kb) {
      const int idx = ((kb & 1) << 5) + koff;
#pragma unroll
      for (int rg = 0; rg < 4; ++rg) {
        short8 a;
        if (kb < 2) {
          a = *reinterpret_cast<const short8*>(h0bf + (size_t)gnc[rg] * 64 + idx);
        } else if (kb < 4) {
          a = *reinterpret_cast<const short8*>(agghl + (size_t)gnc[rg] * 128 + idx);
        } else if (kb < 6) {
          a = *reinterpret_cast<const short8*>(l1bf + (size_t)gnc[rg] * 64 + idx);
        } else {
          a = *reinterpret_cast<const short8*>(agghl + (size_t)gnc[rg] * 128 + 64 + idx);
        }
        acc[rg][0] = __builtin_amdgcn_mfma_f32_16x16x32_bf16(a, breg[kb][0], acc[rg][0], 0, 0, 0);
        acc[rg][1] = __builtin_amdgcn_mfma_f32_16x16x32_bf16(a, breg[kb][1], acc[rg][1], 0, 0, 0);
        acc[rg][2] = __builtin_amdgcn_mfma_f32_16x16x32_bf16(a, breg[kb][2], acc[rg][2], 0, 0, 0);
        acc[rg][3] = __builtin_amdgcn_mfma_f32_16x16x32_bf16(a, breg[kb][3], acc[rg][3], 0, 0, 0);
      }
    }
    __syncthreads();  // all l1bf/h0bf A-reads complete before in-place writes

    float* cst1 = cst + (size_t)NN * 64;
    const float wci = wc[192 + k], wcf = wc[256 + k], wco = wc[320 + k];
    const float bi = bias[256 + k], bfg = bias[320 + k], bc = bias[384 + k], bo = bias[448 + k];
#pragma unroll
    for (int rg = 0; rg < 4; ++rg) {
#pragma unroll
      for (int r = 0; r < 4; ++r) {
        int n = nb + rg * 16 + kg * 4 + r;
        if (n < n_nodes) {
          size_t off = (size_t)n * 64 + k;
          float c_old = cst1[off];
          float ig = sigm(acc[rg][0][r] + wci * c_old + bi);
          float fg = sigm(acc[rg][1][r] + wcf * c_old + bfg);
          float ct = tanh_f(acc[rg][2][r] + bc);
          float nc = fg * c_old + ig * ct;
          float og = sigm(acc[rg][3][r] + wco * nc + bo);
          float nh = og * tanh_f(nc);
          cst1[off] = nc;
          u16 hb = f2b(nh);
          l1bf[off] = hb;
          hq[(size_t)n * 128 + 64 + k] = f2q(nh);
          Hsm[(rg * 16 + kg * 4 + r) * 64 + k] = hb;
          if (wf1) hf32[(size_t)NN * 64 + off] = nh;
        }
      }
    }
  }

  __syncthreads();
  // ===== out-proj: outs[t] = H(64x64) @ Wout + bout =====
  {
    short8 bw[2][2];
#pragma unroll
    for (int kb = 0; kb < 2; ++kb)
#pragma unroll
      for (int fi = 0; fi < 2; ++fi)
        bw[kb][fi] = *reinterpret_cast<const short8*>(wproj + (((kb * 2 + fi) * 64 + lane) << 3));
    short8 a0 = *reinterpret_cast<const short8*>(&Hsm[(w * 16 + cl) * 64 + kg * 8]);
    short8 a1 = *reinterpret_cast<const short8*>(&Hsm[(w * 16 + cl) * 64 + 32 + kg * 8]);
    f32x4 p0 = z4, p1 = z4;
    p0 = __builtin_amdgcn_mfma_f32_16x16x32_bf16(a0, bw[0][0], p0, 0, 0, 0);
    p0 = __builtin_amdgcn_mfma_f32_16x16x32_bf16(a1, bw[1][0], p0, 0, 0, 0);
    p1 = __builtin_amdgcn_mfma_f32_16x16x32_bf16(a0, bw[0][1], p1, 0, 0, 0);
    p1 = __builtin_amdgcn_mfma_f32_16x16x32_bf16(a1, bw[1][1], p1, 0, 0, 0);
    const float bo0 = boutp[cl], bo1 = boutp[16 + cl];
#pragma unroll
    for (int r = 0; r < 4; ++r) {
      int n = nb + w * 16 + kg * 4 + r;
      if (n < n_nodes) {
        outp[(size_t)n * OD + cl] = p0[r] + bo0;
        outp[(size_t)n * OD + 16 + cl] = p1[r] + bo1;
      }
    }
  }

  // ================== part 2: layer-0 gates (step t+1) ==================
  if (do0) {
    short8 breg[8][4];
#pragma unroll
    for (int kb = 0; kb < 8; ++kb)
#pragma unroll
      for (int fl = 0; fl < 4; ++fl)
        breg[kb][fl] = *reinterpret_cast<const short8*>(
            bprep0 + (kb << 13) + (((w << 2) + fl) << 9) + (lane << 3));

    f32x4 acc[4][4];
#pragma unroll
    for (int a = 0; a < 4; ++a)
#pragma unroll
      for (int b = 0; b < 4; ++b) acc[a][b] = z4;

#pragma unroll
    for (int kb = 0; kb < 8; ++kb) {
      const int idx = ((kb & 1) << 5) + koff;
#pragma unroll
      for (int rg = 0; rg < 4; ++rg) {
        short8 a;
        if (kb < 2) {
          const float* rp = xnext + (size_t)gnc[rg] * 64 + idx;
          a = s8_from_f32(*reinterpret_cast<const float4*>(rp),
                          *reinterpret_cast<const float4*>(rp + 4));
        } else if (kb < 4) {
          a = s8_from_fp8(*reinterpret_cast<const uint2*>(aggxqnext + (size_t)gnc[rg] * 64 + idx));
        } else if (kb < 6) {
          a = *reinterpret_cast<const short8*>(h0bf + (size_t)gnc[rg] * 64 + idx);
        } else {
          a = *reinterpret_cast<const short8*>(agghl + (size_t)gnc[rg] * 128 + idx);
        }
        acc[rg][0] = __builtin_amdgcn_mfma_f32_16x16x32_bf16(a, breg[kb][0], acc[rg][0], 0, 0, 0);
        acc[rg][1] = __builtin_amdgcn_mfma_f32_16x16x32_bf16(a, breg[kb][1], acc[rg][1], 0, 0, 0);
        acc[rg][2] = __builtin_amdgcn_mfma_f32_16x16x32_bf16(a, breg[kb][2], acc[rg][2], 0, 0, 0);
        acc[rg][3] = __builtin_amdgcn_mfma_f32_16x16x32_bf16(a, breg[kb][3], acc[rg][3], 0, 0, 0);
      }
    }
    __syncthreads();  // all h0bf A-reads complete before in-place writes

    const float wci = wc[k], wcf = wc[64 + k], wco = wc[128 + k];
    const float bi = bias[k], bfg = bias[64 + k], bc = bias[128 + k], bo = bias[192 + k];
#pragma unroll
    for (int rg = 0; rg < 4; ++rg) {
#pragma unroll
      for (int r = 0; r < 4; ++r) {
        int n = nb + rg * 16 + kg * 4 + r;
        if (n < n_nodes) {
          size_t off = (size_t)n * 64 + k;
          float c_old = cst[off];
          float ig = sigm(acc[rg][0][r] + wci * c_old + bi);
          float fg = sigm(acc[rg][1][r] + wcf * c_old + bfg);
          float ct = tanh_f(acc[rg][2][r] + bc);
          float nc = fg * c_old + ig * ct;
          float og = sigm(acc[rg][3][r] + wco * nc + bo);
          float nh = og * tanh_f(nc);
          cst[off] = nc;
          h0bf[off] = f2b(nh);
          hq[(size_t)n * 128 + k] = f2q(nh);
          if (wf0) hf32[off] = nh;
        }
      }
    }
  }
}

extern "C" void kernel_launch(void* const* d_in, const int* in_sizes, int n_in,
                              void* d_out, int out_size, void* d_ws, size_t ws_size,
                              hipStream_t stream) {
  const float* x = (const float*)d_in[0];
  const float* h0 = (const float*)d_in[1];
  const float* c0 = (const float*)d_in[2];
  const float* Wxs = (const float*)d_in[3];
  const float* Wxn = (const float*)d_in[4];
  const float* Whs = (const float*)d_in[5];
  const float* Whn = (const float*)d_in[6];
  const float* wc = (const float*)d_in[7];
  const float* bias = (const float*)d_in[8];
  const float* Wout = (const float*)d_in[9];
  const float* bout = (const float*)d_in[10];
  const int* src = (const int*)d_in[11];
  const int* dst = (const int*)d_in[12];

  float* out = (float*)d_out;
  float* outs = out;                                   // [T][N][O]
  float* hstate = out + (size_t)T_STEPS * NN * OD;     // [2][N][64] fp32 (final)
  float* cstate = hstate + (size_t)2 * NN * HD;        // [2][N][64] fp32 (live)

  char* p = (char*)d_ws;
  auto alloc = [&](size_t bytes) {
    char* r = p;
    p += (bytes + 255) & ~(size_t)255;
    return r;
  };
  int* csr = (int*)alloc((size_t)EE * 4);
  u8* XQ = (u8*)alloc((size_t)NN * 768);        // x fp8, node-major [N][T*64]
  uint2* binned = (uint2*)XQ;                   // alias: binned dead before XQ written
  u8* AGGXq = (u8*)alloc((size_t)T_STEPS * NN * 64);  // [T][N][64] fp8
  int* row_ptr = (int*)alloc((size_t)(NN + 1) * 4);
  int* cursor = (int*)alloc((size_t)NN * 4);
  int* deg = (int*)alloc((size_t)NN * 4);
  int* excl = (int*)alloc((size_t)NN * 4);
  int* btot = (int*)alloc(128 * 4);
  int* boffs = (int*)alloc(128 * 4);
  int* bcnt = (int*)alloc(NBK * 4);
  int* bcur = (int*)alloc(NBK * 4);
  float* deg_inv = (float*)alloc((size_t)NN * 4);
  u16* H0bf = (u16*)alloc((size_t)NN * 64 * 2);   // h_l0 bf16
  u16* L1bf = (u16*)alloc((size_t)NN * 64 * 2);   // h_l1 bf16
  u8* HQ = (u8*)alloc((size_t)NN * 128);          // [h_l0 | h_l1] fp8 pair
  u16* AGGHL = (u16*)alloc((size_t)NN * 128 * 2); // [agg(h_l0) | agg(h_l1)] bf16
  u16* bprep = (u16*)alloc((size_t)2 * 65536 * 2);
  u16* wprep = (u16*)alloc((size_t)2048 * 2);

  const int nscan = (NN + 1023) / 1024;   // 98
  const int nchunk = (EE + 4095) / 4096;  // 782

  // prologue: bucketed CSR build
  hipMemsetAsync(deg, 0, (size_t)NN * 4, stream);
  hipMemsetAsync(bcnt, 0, (size_t)NBK * 4, stream);
  k_bhist<<<nchunk, 256, 0, stream>>>(dst, bcnt, EE);
  k_bscan<<<1, 512, 0, stream>>>(bcnt, bcur);
  k_bscatter<<<nchunk, 256, 0, stream>>>(src, dst, bcur, binned, EE);
  k_count2<<<(EE + 255) / 256, 256, 0, stream>>>(binned, deg, EE);
  k_scanA<<<nscan, 1024, 0, stream>>>(deg, excl, btot, NN);
  k_scanB<<<1, 128, 0, stream>>>(btot, boffs, nscan);
  k_scanC<<<nscan, 1024, 0, stream>>>(deg, excl, boffs, row_ptr, cursor, deg_inv, NN);
  k_scatter2<<<(EE + 255) / 256, 256, 0, stream>>>(binned, cursor, csr, EE);
  // weight prep + state init + batched x processing (XQ overwrites binned)
  k_prep<<<512, 256, 0, stream>>>(Wxs, Wxn, Whs, Whn, bprep);
  k_prepw<<<8, 256, 0, stream>>>(Wout, wprep);
  k_convxall<<<(T_STEPS * NN * 8 + 255) / 256, 256, 0, stream>>>(x, XQ);
  k_inith<<<NN * 8 / 256, 256, 0, stream>>>(h0, H0bf, L1bf, HQ);
  hipMemcpyAsync(cstate, c0, (size_t)2 * NN * HD * 4, hipMemcpyDeviceToDevice, stream);
  k_aggx<<<(NN + 3) / 4, 256, 0, stream>>>(XQ, row_ptr, csr, deg_inv, AGGXq);
  k_agg_pair<<<(NN + 3) / 4, 256, 0, stream>>>(HQ, row_ptr, csr, deg_inv, AGGHL);

  // step 0, layer 0 (standalone)
  k_gates0<<<(NN + 63) / 64, 256, 0, stream>>>(
      x, AGGXq, H0bf, AGGHL, HQ, cstate, hstate, bprep, wc, bias, NN, 0);

  for (int t = 0; t < T_STEPS; ++t) {
    int do0 = (t < T_STEPS - 1) ? 1 : 0;
    int wf0 = (t == T_STEPS - 2) ? 1 : 0;  // gates0-part computes step 11 layer-0 h
    int wf1 = (t == T_STEPS - 1) ? 1 : 0;
    // one pair gather: agg(h_l0 new) -> AGGHL[:,0:64], agg(h_l1 old) -> AGGHL[:,64:]
    k_agg_pair<<<(NN + 3) / 4, 256, 0, stream>>>(HQ, row_ptr, csr, deg_inv, AGGHL);
    // fused: layer-1 gates (t) + out-proj + layer-0 gates (t+1)
    const float* xn = do0 ? (x + (size_t)(t + 1) * NN * HD) : x;
    const u8* an = do0 ? (AGGXq + (size_t)(t + 1) * NN * 64) : AGGXq;
    k_gates10<<<(NN + 63) / 64, 256, 0, stream>>>(
        H0bf, AGGHL, L1bf, HQ, cstate, hstate,
        bprep, bprep + 65536, wc, bias,
        wprep, bout, outs + (size_t)t * NN * OD,
        xn, an, NN, do0, wf0, wf1);
  }
}

// Round 8
// 2984.249 us; speedup vs baseline: 1.1842x; 1.1842x over previous
//
#include <hip/hip_runtime.h>

#define T_STEPS 12
#define NN 100000
#define EE 3200000
#define HD 64
#define OD 32
#define NBK 391  // (NN+255)/256 buckets of 256 nodes

typedef __attribute__((ext_vector_type(8))) short short8;
typedef __attribute__((ext_vector_type(4))) float f32x4;
typedef __attribute__((ext_vector_type(2))) float f32x2;
typedef unsigned short u16;
typedef unsigned char u8;

__device__ __forceinline__ u16 f2b(float x) {
  union { float f; unsigned u; } v; v.f = x;
  unsigned r = v.u + 0x7FFFu + ((v.u >> 16) & 1u);
  return (u16)(r >> 16);
}
__device__ __forceinline__ u16 f2h(float x) {
  union { _Float16 h; u16 s; } u; u.h = (_Float16)x; return u.s;
}
__device__ __forceinline__ float h2f(u16 s) {
  union { u16 s; _Float16 h; } u; u.s = s; return (float)u.h;
}
__device__ __forceinline__ float sigm(float x) {
  x = fminf(fmaxf(x, -30.f), 30.f);
  return 1.0f / (1.0f + __expf(-x));
}
__device__ __forceinline__ float tanh_f(float x) {
  x = fminf(fmaxf(x, -15.f), 15.f);
  float e = __expf(2.0f * x);
  return (e - 1.0f) / (e + 1.0f);
}

// fp8 e4m3 (OCP) helpers via gfx950 HW converts
__device__ __forceinline__ uint2 pack8_fp8(const float* f) {
  unsigned lo = 0, hi = 0;
  lo = __builtin_amdgcn_cvt_pk_fp8_f32(f[0], f[1], lo, false);
  lo = __builtin_amdgcn_cvt_pk_fp8_f32(f[2], f[3], lo, true);
  hi = __builtin_amdgcn_cvt_pk_fp8_f32(f[4], f[5], hi, false);
  hi = __builtin_amdgcn_cvt_pk_fp8_f32(f[6], f[7], hi, true);
  return make_uint2(lo, hi);
}
__device__ __forceinline__ u8 f2q(float x) {
  return (u8)(__builtin_amdgcn_cvt_pk_fp8_f32(x, 0.f, 0u, false) & 0xFFu);
}
__device__ __forceinline__ void acc8_fp8(uint2 v, float* a) {
  f32x2 p0 = __builtin_amdgcn_cvt_pk_f32_fp8(v.x, false);
  f32x2 p1 = __builtin_amdgcn_cvt_pk_f32_fp8(v.x, true);
  f32x2 p2 = __builtin_amdgcn_cvt_pk_f32_fp8(v.y, false);
  f32x2 p3 = __builtin_amdgcn_cvt_pk_f32_fp8(v.y, true);
  a[0] += p0[0]; a[1] += p0[1]; a[2] += p1[0]; a[3] += p1[1];
  a[4] += p2[0]; a[5] += p2[1]; a[6] += p3[0]; a[7] += p3[1];
}
__device__ __forceinline__ void dec16_acc2(uint4 q, f32x2* a) {
  a[0] += __builtin_amdgcn_cvt_pk_f32_fp8(q.x, false);
  a[1] += __builtin_amdgcn_cvt_pk_f32_fp8(q.x, true);
  a[2] += __builtin_amdgcn_cvt_pk_f32_fp8(q.y, false);
  a[3] += __builtin_amdgcn_cvt_pk_f32_fp8(q.y, true);
  a[4] += __builtin_amdgcn_cvt_pk_f32_fp8(q.z, false);
  a[5] += __builtin_amdgcn_cvt_pk_f32_fp8(q.z, true);
  a[6] += __builtin_amdgcn_cvt_pk_f32_fp8(q.w, false);
  a[7] += __builtin_amdgcn_cvt_pk_f32_fp8(q.w, true);
}
__device__ __forceinline__ short8 s8_from_fp8(uint2 q) {
  f32x2 p0 = __builtin_amdgcn_cvt_pk_f32_fp8(q.x, false);
  f32x2 p1 = __builtin_amdgcn_cvt_pk_f32_fp8(q.x, true);
  f32x2 p2 = __builtin_amdgcn_cvt_pk_f32_fp8(q.y, false);
  f32x2 p3 = __builtin_amdgcn_cvt_pk_f32_fp8(q.y, true);
  short8 o;
  o[0] = (short)f2b(p0[0]); o[1] = (short)f2b(p0[1]);
  o[2] = (short)f2b(p1[0]); o[3] = (short)f2b(p1[1]);
  o[4] = (short)f2b(p2[0]); o[5] = (short)f2b(p2[1]);
  o[6] = (short)f2b(p3[0]); o[7] = (short)f2b(p3[1]);
  return o;
}
__device__ __forceinline__ short8 s8_from_f32(float4 a, float4 b) {
  short8 o;
  o[0] = (short)f2b(a.x); o[1] = (short)f2b(a.y);
  o[2] = (short)f2b(a.z); o[3] = (short)f2b(a.w);
  o[4] = (short)f2b(b.x); o[5] = (short)f2b(b.y);
  o[6] = (short)f2b(b.z); o[7] = (short)f2b(b.w);
  return o;
}

// ================= bucketed CSR build =================
__global__ __launch_bounds__(256) void k_bhist(const int* __restrict__ dst,
                                               int* __restrict__ bcnt, int E) {
  __shared__ int h[NBK];
  for (int i = threadIdx.x; i < NBK; i += 256) h[i] = 0;
  __syncthreads();
  int base = blockIdx.x * 4096;
#pragma unroll
  for (int i = 0; i < 16; ++i) {
    int e = base + i * 256 + threadIdx.x;
    if (e < E) atomicAdd(&h[dst[e] >> 8], 1);
  }
  __syncthreads();
  for (int i = threadIdx.x; i < NBK; i += 256)
    if (h[i]) atomicAdd(&bcnt[i], h[i]);
}

__global__ __launch_bounds__(512) void k_bscan(const int* __restrict__ bcnt,
                                               int* __restrict__ bcur) {
  __shared__ int buf[512];
  int tid = threadIdx.x;
  int v = (tid < NBK) ? bcnt[tid] : 0;
  buf[tid] = v;
  __syncthreads();
  for (int off = 1; off < 512; off <<= 1) {
    int t = (tid >= off) ? buf[tid - off] : 0;
    __syncthreads();
    buf[tid] += t;
    __syncthreads();
  }
  if (tid < NBK) bcur[tid] = buf[tid] - v;
}

__global__ __launch_bounds__(256) void k_bscatter(const int* __restrict__ src,
                                                  const int* __restrict__ dst,
                                                  int* __restrict__ bcur,
                                                  uint2* __restrict__ binned, int E) {
  __shared__ int h[NBK];
  __shared__ int base[NBK];
  __shared__ int cur[NBK];
  for (int i = threadIdx.x; i < NBK; i += 256) { h[i] = 0; cur[i] = 0; }
  __syncthreads();
  int b0 = blockIdx.x * 4096;
  int d[16], s[16];
#pragma unroll
  for (int i = 0; i < 16; ++i) {
    int e = b0 + i * 256 + threadIdx.x;
    if (e < E) {
      d[i] = dst[e];
      s[i] = src[e];
      atomicAdd(&h[d[i] >> 8], 1);
    } else d[i] = -1;
  }
  __syncthreads();
  for (int i = threadIdx.x; i < NBK; i += 256)
    if (h[i]) base[i] = atomicAdd(&bcur[i], h[i]);
  __syncthreads();
#pragma unroll
  for (int i = 0; i < 16; ++i) {
    if (d[i] >= 0) {
      int bk = d[i] >> 8;
      int r = atomicAdd(&cur[bk], 1);
      binned[base[bk] + r] = make_uint2((unsigned)s[i], (unsigned)d[i]);
    }
  }
}

__global__ __launch_bounds__(256) void k_count2(const uint2* __restrict__ binned,
                                                int* __restrict__ deg, int E) {
  int e = blockIdx.x * 256 + threadIdx.x;
  if (e < E) atomicAdd(&deg[binned[e].y], 1);
}

__global__ __launch_bounds__(1024) void k_scanA(const int* __restrict__ deg,
                                                int* __restrict__ excl,
                                                int* __restrict__ btot, int n) {
  __shared__ int buf[1024];
  int tid = threadIdx.x;
  int i = blockIdx.x * 1024 + tid;
  int v = (i < n) ? deg[i] : 0;
  buf[tid] = v;
  __syncthreads();
  for (int off = 1; off < 1024; off <<= 1) {
    int t = (tid >= off) ? buf[tid - off] : 0;
    __syncthreads();
    buf[tid] += t;
    __syncthreads();
  }
  if (i < n) excl[i] = buf[tid] - v;
  if (tid == 1023) btot[blockIdx.x] = buf[1023];
}

__global__ __launch_bounds__(128) void k_scanB(const int* __restrict__ btot,
                                               int* __restrict__ boffs, int nb) {
  __shared__ int buf[128];
  int tid = threadIdx.x;
  int v = (tid < nb) ? btot[tid] : 0;
  buf[tid] = v;
  __syncthreads();
  for (int off = 1; off < 128; off <<= 1) {
    int t = (tid >= off) ? buf[tid - off] : 0;
    __syncthreads();
    buf[tid] += t;
    __syncthreads();
  }
  if (tid < nb) boffs[tid] = buf[tid] - v;
}

__global__ __launch_bounds__(1024) void k_scanC(const int* __restrict__ deg,
                                                const int* __restrict__ excl,
                                                const int* __restrict__ boffs,
                                                int* __restrict__ row_ptr,
                                                int* __restrict__ cursor,
                                                float* __restrict__ deg_inv, int n) {
  int i = blockIdx.x * 1024 + threadIdx.x;
  if (i < n) {
    int v = excl[i] + boffs[blockIdx.x];
    int d = deg[i];
    row_ptr[i] = v;
    cursor[i] = v;
    deg_inv[i] = d ? (1.0f / (float)d) : 0.0f;
    if (i == n - 1) row_ptr[n] = v + d;
  }
}

__global__ __launch_bounds__(256) void k_scatter2(const uint2* __restrict__ binned,
                                                  int* __restrict__ cursor,
                                                  int* __restrict__ csr, int E) {
  int e = blockIdx.x * 256 + threadIdx.x;
  if (e < E) {
    uint2 p = binned[e];
    int pos = atomicAdd(&cursor[p.y], 1);
    csr[pos] = (int)p.x;
  }
}

// ---------------- weight prep: fragment-ordered bf16 B ----------------
__global__ __launch_bounds__(256) void k_prep(const float* __restrict__ Wxs,
                                              const float* __restrict__ Wxn,
                                              const float* __restrict__ Whs,
                                              const float* __restrict__ Whn,
                                              u16* __restrict__ bprep) {
  int idx = blockIdx.x * 256 + threadIdx.x;  // 0..131071
  int l = idx >> 16;
  int kb = (idx >> 13) & 7;
  int fi = (idx >> 9) & 15;
  int ln = (idx >> 3) & 63;
  int j = idx & 7;
  int fc = kb * 32 + ((ln >> 4) << 3) + j;
  int g = fi & 3;
  int kk = ((fi >> 2) << 4) + (ln & 15);
  int t = fc >> 6, f = fc & 63;
  const float* tabs[4] = {Wxs, Wxn, Whs, Whn};
  bprep[idx] = f2b(tabs[t][((size_t)(l * 4 + g) * 64 + f) * 64 + kk]);
}

__global__ __launch_bounds__(256) void k_prepw(const float* __restrict__ Wout,
                                               u16* __restrict__ wp) {
  int idx = blockIdx.x * 256 + threadIdx.x;  // 0..2047
  int kb = idx >> 10;
  int fi = (idx >> 9) & 1;
  int ln = (idx >> 3) & 63;
  int j = idx & 7;
  int k = kb * 32 + ((ln >> 4) << 3) + j;
  int o = fi * 16 + (ln & 15);
  wp[idx] = f2b(Wout[k * 32 + o]);
}

// ---------------- batch x -> transposed fp8 XQ[N][T*64] ----------------
__global__ __launch_bounds__(256) void k_convxall(const float* __restrict__ x,
                                                  u8* __restrict__ XQ) {
  int tid = blockIdx.x * 256 + threadIdx.x;  // (t*NN + n)*8 + j
  int j = tid & 7;
  int tn = tid >> 3;
  int n = tn % NN;
  int t = tn / NN;
  const float* rp = x + (size_t)tn * 64 + j * 8;
  float4 v0 = *reinterpret_cast<const float4*>(rp);
  float4 v1 = *reinterpret_cast<const float4*>(rp + 4);
  float f[8] = {v0.x, v0.y, v0.z, v0.w, v1.x, v1.y, v1.z, v1.w};
  *reinterpret_cast<uint2*>(XQ + (size_t)n * 768 + t * 64 + j * 8) = pack8_fp8(f);
}

// -------- init h (bf16 tables + fp8 HQ pair) and c (fp16) --------
__global__ __launch_bounds__(256) void k_inith(const float* __restrict__ h0,
                                               const float* __restrict__ c0,
                                               u16* __restrict__ H0bf,
                                               u16* __restrict__ L1bf,
                                               u8* __restrict__ HQ,
                                               u16* __restrict__ C16) {
  int idx = blockIdx.x * 256 + threadIdx.x;  // N*8
  int n = idx >> 3, j = idx & 7;
#pragma unroll
  for (int L = 0; L < 2; ++L) {
    const float* rp = h0 + (size_t)L * NN * 64 + (size_t)n * 64 + j * 8;
    float4 v0 = *reinterpret_cast<const float4*>(rp);
    float4 v1 = *reinterpret_cast<const float4*>(rp + 4);
    float f[8] = {v0.x, v0.y, v0.z, v0.w, v1.x, v1.y, v1.z, v1.w};
    short8 o;
#pragma unroll
    for (int i = 0; i < 8; ++i) o[i] = (short)f2b(f[i]);
    if (L == 0)
      *reinterpret_cast<short8*>(H0bf + (size_t)n * 64 + j * 8) = o;
    else
      *reinterpret_cast<short8*>(L1bf + (size_t)n * 64 + j * 8) = o;
    *reinterpret_cast<uint2*>(HQ + (size_t)n * 128 + L * 64 + j * 8) = pack8_fp8(f);
    // c init -> fp16
    const float* cp = c0 + (size_t)L * NN * 64 + (size_t)n * 64 + j * 8;
    float4 c0v = *reinterpret_cast<const float4*>(cp);
    float4 c1v = *reinterpret_cast<const float4*>(cp + 4);
    float cf[8] = {c0v.x, c0v.y, c0v.z, c0v.w, c1v.x, c1v.y, c1v.z, c1v.w};
    short8 oc;
#pragma unroll
    for (int i = 0; i < 8; ++i) oc[i] = (short)f2h(cf[i]);
    *reinterpret_cast<short8*>(C16 + (size_t)L * NN * 64 + (size_t)n * 64 + j * 8) = oc;
  }
}

// ---------------- batched x aggregation: all T steps in one pass ------------
__global__ __launch_bounds__(256) void k_aggx(const u8* __restrict__ XQ,
                                              const int* __restrict__ row_ptr,
                                              const int* __restrict__ csr,
                                              const float* __restrict__ deg_inv,
                                              u8* __restrict__ AGGXq) {
  int node = blockIdx.x * 4 + (threadIdx.x >> 6);
  int lane = threadIdx.x & 63;
  int g = lane >> 4, m = lane & 15;
  int start = row_ptr[node], end = row_ptr[node + 1];
  f32x2 acc[3][8];
#pragma unroll
  for (int p = 0; p < 3; ++p)
#pragma unroll
    for (int i = 0; i < 8; ++i) acc[p][i] = (f32x2){0.f, 0.f};
  int e = start + g;
  for (; e + 4 < end; e += 8) {
    int s0 = csr[e], s1 = csr[e + 4];
    const u8* r0 = XQ + (size_t)s0 * 768 + m * 16;
    const u8* r1 = XQ + (size_t)s1 * 768 + m * 16;
#pragma unroll
    for (int p = 0; p < 3; ++p) {
      uint4 q0 = *reinterpret_cast<const uint4*>(r0 + p * 256);
      uint4 q1 = *reinterpret_cast<const uint4*>(r1 + p * 256);
      dec16_acc2(q0, acc[p]);
      dec16_acc2(q1, acc[p]);
    }
  }
  if (e < end) {
    int s0 = csr[e];
    const u8* r0 = XQ + (size_t)s0 * 768 + m * 16;
#pragma unroll
    for (int p = 0; p < 3; ++p) {
      uint4 q0 = *reinterpret_cast<const uint4*>(r0 + p * 256);
      dec16_acc2(q0, acc[p]);
    }
  }
#pragma unroll
  for (int off = 16; off < 64; off <<= 1)
#pragma unroll
    for (int p = 0; p < 3; ++p)
#pragma unroll
      for (int i = 0; i < 8; ++i) {
        acc[p][i][0] += __shfl_xor(acc[p][i][0], off);
        acc[p][i][1] += __shfl_xor(acc[p][i][1], off);
      }
  if (g == 0) {
    float sc = deg_inv[node];
#pragma unroll
    for (int p = 0; p < 3; ++p) {
      float f[16];
#pragma unroll
      for (int i = 0; i < 8; ++i) {
        f[i * 2] = acc[p][i][0] * sc;
        f[i * 2 + 1] = acc[p][i][1] * sc;
      }
      uint4 o;
      unsigned w;
      w = 0; w = __builtin_amdgcn_cvt_pk_fp8_f32(f[0], f[1], w, false);
      w = __builtin_amdgcn_cvt_pk_fp8_f32(f[2], f[3], w, true); o.x = w;
      w = 0; w = __builtin_amdgcn_cvt_pk_fp8_f32(f[4], f[5], w, false);
      w = __builtin_amdgcn_cvt_pk_fp8_f32(f[6], f[7], w, true); o.y = w;
      w = 0; w = __builtin_amdgcn_cvt_pk_fp8_f32(f[8], f[9], w, false);
      w = __builtin_amdgcn_cvt_pk_fp8_f32(f[10], f[11], w, true); o.z = w;
      w = 0; w = __builtin_amdgcn_cvt_pk_fp8_f32(f[12], f[13], w, false);
      w = __builtin_amdgcn_cvt_pk_fp8_f32(f[14], f[15], w, true); o.w = w;
      int t = p * 4 + (m >> 2);
      *reinterpret_cast<uint4*>(AGGXq + ((size_t)t * NN + node) * 64 + (m & 3) * 16) = o;
    }
  }
}

// ------- dual mean aggregation over HQ [N][128] fp8 -> two [N][64] bf16 -----
__global__ __launch_bounds__(256) void k_agg_pair(const u8* __restrict__ Q,
                                                  const int* __restrict__ row_ptr,
                                                  const int* __restrict__ csr,
                                                  const float* __restrict__ deg_inv,
                                                  u16* __restrict__ out0,
                                                  u16* __restrict__ out1) {
  int node = blockIdx.x * 4 + (threadIdx.x >> 6);
  int lane = threadIdx.x & 63;
  int g = lane >> 4, m = lane & 15;
  int start = row_ptr[node], end = row_ptr[node + 1];
  float a[8] = {0, 0, 0, 0, 0, 0, 0, 0};
  int e = start + g;
  for (; e + 12 < end; e += 16) {
    int s0 = csr[e], s1 = csr[e + 4], s2 = csr[e + 8], s3 = csr[e + 12];
    uint2 v0 = *reinterpret_cast<const uint2*>(Q + (size_t)s0 * 128 + m * 8);
    uint2 v1 = *reinterpret_cast<const uint2*>(Q + (size_t)s1 * 128 + m * 8);
    uint2 v2 = *reinterpret_cast<const uint2*>(Q + (size_t)s2 * 128 + m * 8);
    uint2 v3 = *reinterpret_cast<const uint2*>(Q + (size_t)s3 * 128 + m * 8);
    acc8_fp8(v0, a); acc8_fp8(v1, a); acc8_fp8(v2, a); acc8_fp8(v3, a);
  }
  if (e + 4 < end) {
    int s0 = csr[e], s1 = csr[e + 4];
    uint2 v0 = *reinterpret_cast<const uint2*>(Q + (size_t)s0 * 128 + m * 8);
    uint2 v1 = *reinterpret_cast<const uint2*>(Q + (size_t)s1 * 128 + m * 8);
    acc8_fp8(v0, a); acc8_fp8(v1, a);
    e += 8;
  }
  if (e < end) {
    int s0 = csr[e];
    uint2 v0 = *reinterpret_cast<const uint2*>(Q + (size_t)s0 * 128 + m * 8);
    acc8_fp8(v0, a);
  }
#pragma unroll
  for (int off = 16; off < 64; off <<= 1) {
#pragma unroll
    for (int i = 0; i < 8; ++i) a[i] += __shfl_xor(a[i], off);
  }
  if (g == 0) {
    float sc = deg_inv[node];
    short8 o;
#pragma unroll
    for (int i = 0; i < 8; ++i) o[i] = (short)f2b(a[i] * sc);
    if (m < 8)
      *reinterpret_cast<short8*>(out0 + (size_t)node * 64 + m * 8) = o;
    else
      *reinterpret_cast<short8*>(out1 + (size_t)node * 64 + (m - 8) * 8) = o;
  }
}

// ---------------- layer-0 gates ----------------
__global__ __launch_bounds__(256, 2) void k_gates0(
    const float* __restrict__ xin, const u8* __restrict__ aggxq,
    u16* __restrict__ h0bf, const u16* __restrict__ aggh0,
    u8* __restrict__ hq, u16* __restrict__ c16,
    float* __restrict__ hf32, float* __restrict__ cf32,
    const u16* __restrict__ bprepl,
    const float* __restrict__ wcl, const float* __restrict__ biasl,
    int n_nodes, int wf) {
  const int tid = threadIdx.x;
  const int lane = tid & 63;
  const int w = tid >> 6;
  const int nb = blockIdx.x * 64;
  const int cl = lane & 15;
  const int kg = lane >> 4;

  short8 breg[8][4];
#pragma unroll
  for (int kb = 0; kb < 8; ++kb)
#pragma unroll
    for (int fl = 0; fl < 4; ++fl)
      breg[kb][fl] = *reinterpret_cast<const short8*>(
          bprepl + (kb << 13) + (((w << 2) + fl) << 9) + (lane << 3));

  int gnc[4];
#pragma unroll
  for (int rg = 0; rg < 4; ++rg) {
    int g = nb + rg * 16 + cl;
    gnc[rg] = (g < n_nodes) ? g : (n_nodes - 1);
  }

  f32x4 acc[4][4];
  f32x4 z4 = {0.f, 0.f, 0.f, 0.f};
#pragma unroll
  for (int a = 0; a < 4; ++a)
#pragma unroll
    for (int b = 0; b < 4; ++b) acc[a][b] = z4;

  const int koff = kg << 3;
#pragma unroll
  for (int kb = 0; kb < 8; ++kb) {
    const int idx = ((kb & 1) << 5) + koff;
#pragma unroll
    for (int rg = 0; rg < 4; ++rg) {
      short8 a;
      if (kb < 2) {
        const float* rp = xin + (size_t)gnc[rg] * 64 + idx;
        a = s8_from_f32(*reinterpret_cast<const float4*>(rp),
                        *reinterpret_cast<const float4*>(rp + 4));
      } else if (kb < 4) {
        a = s8_from_fp8(*reinterpret_cast<const uint2*>(aggxq + (size_t)gnc[rg] * 64 + idx));
      } else if (kb < 6) {
        a = *reinterpret_cast<const short8*>(h0bf + (size_t)gnc[rg] * 64 + idx);
      } else {
        a = *reinterpret_cast<const short8*>(aggh0 + (size_t)gnc[rg] * 64 + idx);
      }
      acc[rg][0] = __builtin_amdgcn_mfma_f32_16x16x32_bf16(a, breg[kb][0], acc[rg][0], 0, 0, 0);
      acc[rg][1] = __builtin_amdgcn_mfma_f32_16x16x32_bf16(a, breg[kb][1], acc[rg][1], 0, 0, 0);
      acc[rg][2] = __builtin_amdgcn_mfma_f32_16x16x32_bf16(a, breg[kb][2], acc[rg][2], 0, 0, 0);
      acc[rg][3] = __builtin_amdgcn_mfma_f32_16x16x32_bf16(a, breg[kb][3], acc[rg][3], 0, 0, 0);
    }
  }
  __syncthreads();  // all h0bf A-reads complete before in-place writes

  const int k = (w << 4) + cl;
  const float wci = wcl[k], wcf = wcl[64 + k], wco = wcl[128 + k];
  const float bi = biasl[k], bfg = biasl[64 + k], bc = biasl[128 + k], bo = biasl[192 + k];
#pragma unroll
  for (int rg = 0; rg < 4; ++rg) {
#pragma unroll
    for (int r = 0; r < 4; ++r) {
      int n = nb + rg * 16 + kg * 4 + r;
      if (n < n_nodes) {
        size_t off = (size_t)n * 64 + k;
        float c_old = h2f(c16[off]);
        float ig = sigm(acc[rg][0][r] + wci * c_old + bi);
        float fg = sigm(acc[rg][1][r] + wcf * c_old + bfg);
        float ct = tanh_f(acc[rg][2][r] + bc);
        float nc = fg * c_old + ig * ct;
        float og = sigm(acc[rg][3][r] + wco * nc + bo);
        float nh = og * tanh_f(nc);
        c16[off] = f2h(nc);
        h0bf[off] = f2b(nh);
        hq[(size_t)n * 128 + k] = f2q(nh);
        if (wf) { hf32[off] = nh; cf32[off] = nc; }
      }
    }
  }
}

// ---------------- layer-1 gates + fused out-proj ----------------
__global__ __launch_bounds__(256, 2) void k_gates1(
    const u16* __restrict__ h0bf, const u16* __restrict__ aggh0,
    const u16* __restrict__ aggh1,
    u16* __restrict__ l1bf, u8* __restrict__ hq, u16* __restrict__ c16,
    float* __restrict__ hf32, float* __restrict__ cf32,
    const u16* __restrict__ bprepl,
    const float* __restrict__ wcl, const float* __restrict__ biasl,
    const u16* __restrict__ wproj, const float* __restrict__ boutp,
    float* __restrict__ outp, int n_nodes, int wf) {
  __shared__ u16 Hsm[64 * 64];  // 8 KB
  const int tid = threadIdx.x;
  const int lane = tid & 63;
  const int w = tid >> 6;
  const int nb = blockIdx.x * 64;
  const int cl = lane & 15;
  const int kg = lane >> 4;

  short8 breg[8][4];
#pragma unroll
  for (int kb = 0; kb < 8; ++kb)
#pragma unroll
    for (int fl = 0; fl < 4; ++fl)
      breg[kb][fl] = *reinterpret_cast<const short8*>(
          bprepl + (kb << 13) + (((w << 2) + fl) << 9) + (lane << 3));

  int gnc[4];
#pragma unroll
  for (int rg = 0; rg < 4; ++rg) {
    int g = nb + rg * 16 + cl;
    gnc[rg] = (g < n_nodes) ? g : (n_nodes - 1);
  }

  f32x4 acc[4][4];
  f32x4 z4 = {0.f, 0.f, 0.f, 0.f};
#pragma unroll
  for (int a = 0; a < 4; ++a)
#pragma unroll
    for (int b = 0; b < 4; ++b) acc[a][b] = z4;

  const int koff = kg << 3;
#pragma unroll
  for (int kb = 0; kb < 8; ++kb) {
    const int idx = ((kb & 1) << 5) + koff;
#pragma unroll
    for (int rg = 0; rg < 4; ++rg) {
      short8 a;
      if (kb < 2) {
        a = *reinterpret_cast<const short8*>(h0bf + (size_t)gnc[rg] * 64 + idx);
      } else if (kb < 4) {
        a = *reinterpret_cast<const short8*>(aggh0 + (size_t)gnc[rg] * 64 + idx);
      } else if (kb < 6) {
        a = *reinterpret_cast<const short8*>(l1bf + (size_t)gnc[rg] * 64 + idx);
      } else {
        a = *reinterpret_cast<const short8*>(aggh1 + (size_t)gnc[rg] * 64 + idx);
      }
      acc[rg][0] = __builtin_amdgcn_mfma_f32_16x16x32_bf16(a, breg[kb][0], acc[rg][0], 0, 0, 0);
      acc[rg][1] = __builtin_amdgcn_mfma_f32_16x16x32_bf16(a, breg[kb][1], acc[rg][1], 0, 0, 0);
      acc[rg][2] = __builtin_amdgcn_mfma_f32_16x16x32_bf16(a, breg[kb][2], acc[rg][2], 0, 0, 0);
      acc[rg][3] = __builtin_amdgcn_mfma_f32_16x16x32_bf16(a, breg[kb][3], acc[rg][3], 0, 0, 0);
    }
  }
  __syncthreads();  // all l1bf A-reads complete before in-place writes

  const int k = (w << 4) + cl;
  const float wci = wcl[k], wcf = wcl[64 + k], wco = wcl[128 + k];
  const float bi = biasl[k], bfg = biasl[64 + k], bc = biasl[128 + k], bo = biasl[192 + k];
#pragma unroll
  for (int rg = 0; rg < 4; ++rg) {
#pragma unroll
    for (int r = 0; r < 4; ++r) {
      int n = nb + rg * 16 + kg * 4 + r;
      if (n < n_nodes) {
        size_t off = (size_t)n * 64 + k;
        float c_old = h2f(c16[off]);
        float ig = sigm(acc[rg][0][r] + wci * c_old + bi);
        float fg = sigm(acc[rg][1][r] + wcf * c_old + bfg);
        float ct = tanh_f(acc[rg][2][r] + bc);
        float nc = fg * c_old + ig * ct;
        float og = sigm(acc[rg][3][r] + wco * nc + bo);
        float nh = og * tanh_f(nc);
        c16[off] = f2h(nc);
        u16 hb = f2b(nh);
        l1bf[off] = hb;
        hq[(size_t)n * 128 + 64 + k] = f2q(nh);
        Hsm[(rg * 16 + kg * 4 + r) * 64 + k] = hb;
        if (wf) { hf32[off] = nh; cf32[off] = nc; }
      }
    }
  }

  __syncthreads();
  short8 bw[2][2];
#pragma unroll
  for (int kb = 0; kb < 2; ++kb)
#pragma unroll
    for (int fi = 0; fi < 2; ++fi)
      bw[kb][fi] = *reinterpret_cast<const short8*>(wproj + (((kb * 2 + fi) * 64 + lane) << 3));
  short8 a0 = *reinterpret_cast<const short8*>(&Hsm[(w * 16 + cl) * 64 + kg * 8]);
  short8 a1 = *reinterpret_cast<const short8*>(&Hsm[(w * 16 + cl) * 64 + 32 + kg * 8]);
  f32x4 p0 = z4, p1 = z4;
  p0 = __builtin_amdgcn_mfma_f32_16x16x32_bf16(a0, bw[0][0], p0, 0, 0, 0);
  p0 = __builtin_amdgcn_mfma_f32_16x16x32_bf16(a1, bw[1][0], p0, 0, 0, 0);
  p1 = __builtin_amdgcn_mfma_f32_16x16x32_bf16(a0, bw[0][1], p1, 0, 0, 0);
  p1 = __builtin_amdgcn_mfma_f32_16x16x32_bf16(a1, bw[1][1], p1, 0, 0, 0);
  const float bo0 = boutp[cl], bo1 = boutp[16 + cl];
#pragma unroll
  for (int r = 0; r < 4; ++r) {
    int n = nb + w * 16 + kg * 4 + r;
    if (n < n_nodes) {
      outp[(size_t)n * OD + cl] = p0[r] + bo0;
      outp[(size_t)n * OD + 16 + cl] = p1[r] + bo1;
    }
  }
}

extern "C" void kernel_launch(void* const* d_in, const int* in_sizes, int n_in,
                              void* d_out, int out_size, void* d_ws, size_t ws_size,
                              hipStream_t stream) {
  const float* x = (const float*)d_in[0];
  const float* h0 = (const float*)d_in[1];
  const float* c0 = (const float*)d_in[2];
  const float* Wxs = (const float*)d_in[3];
  const float* Wxn = (const float*)d_in[4];
  const float* Whs = (const float*)d_in[5];
  const float* Whn = (const float*)d_in[6];
  const float* wc = (const float*)d_in[7];
  const float* bias = (const float*)d_in[8];
  const float* Wout = (const float*)d_in[9];
  const float* bout = (const float*)d_in[10];
  const int* src = (const int*)d_in[11];
  const int* dst = (const int*)d_in[12];

  float* out = (float*)d_out;
  float* outs = out;                                   // [T][N][O]
  float* hstate = out + (size_t)T_STEPS * NN * OD;     // [2][N][64] fp32 (final only)
  float* cstate = hstate + (size_t)2 * NN * HD;        // [2][N][64] fp32 (final only)

  char* p = (char*)d_ws;
  auto alloc = [&](size_t bytes) {
    char* r = p;
    p += (bytes + 255) & ~(size_t)255;
    return r;
  };
  int* csr = (int*)alloc((size_t)EE * 4);
  u8* XQ = (u8*)alloc((size_t)NN * 768);        // x fp8, node-major [N][T*64]
  uint2* binned = (uint2*)XQ;                   // alias: binned dead before XQ written
  u8* AGGXq = (u8*)alloc((size_t)T_STEPS * NN * 64);  // [T][N][64] fp8
  int* row_ptr = (int*)alloc((size_t)(NN + 1) * 4);
  int* cursor = (int*)alloc((size_t)NN * 4);
  int* deg = (int*)alloc((size_t)NN * 4);
  int* excl = (int*)alloc((size_t)NN * 4);
  int* btot = (int*)alloc(128 * 4);
  int* boffs = (int*)alloc(128 * 4);
  int* bcnt = (int*)alloc(NBK * 4);
  int* bcur = (int*)alloc(NBK * 4);
  float* deg_inv = (float*)alloc((size_t)NN * 4);
  u16* H0bf = (u16*)alloc((size_t)NN * 64 * 2);   // h_l0 bf16
  u16* L1bf = (u16*)alloc((size_t)NN * 64 * 2);   // h_l1 bf16
  u8* HQ = (u8*)alloc((size_t)NN * 128);          // [h_l0 | h_l1] fp8 pair
  u16* AGGH0 = (u16*)alloc((size_t)NN * 64 * 2);  // agg(h_l0) bf16
  u16* AGGH1 = (u16*)alloc((size_t)NN * 64 * 2);  // agg(h_l1) bf16
  u16* C16 = (u16*)alloc((size_t)2 * NN * 64 * 2);  // live c fp16 [2][N][64]
  u16* bprep = (u16*)alloc((size_t)2 * 65536 * 2);
  u16* wprep = (u16*)alloc((size_t)2048 * 2);

  const int nscan = (NN + 1023) / 1024;   // 98
  const int nchunk = (EE + 4095) / 4096;  // 782

  // prologue: bucketed CSR build
  hipMemsetAsync(deg, 0, (size_t)NN * 4, stream);
  hipMemsetAsync(bcnt, 0, (size_t)NBK * 4, stream);
  k_bhist<<<nchunk, 256, 0, stream>>>(dst, bcnt, EE);
  k_bscan<<<1, 512, 0, stream>>>(bcnt, bcur);
  k_bscatter<<<nchunk, 256, 0, stream>>>(src, dst, bcur, binned, EE);
  k_count2<<<(EE + 255) / 256, 256, 0, stream>>>(binned, deg, EE);
  k_scanA<<<nscan, 1024, 0, stream>>>(deg, excl, btot, NN);
  k_scanB<<<1, 128, 0, stream>>>(btot, boffs, nscan);
  k_scanC<<<nscan, 1024, 0, stream>>>(deg, excl, boffs, row_ptr, cursor, deg_inv, NN);
  k_scatter2<<<(EE + 255) / 256, 256, 0, stream>>>(binned, cursor, csr, EE);
  // weight prep + state init + batched x processing (XQ overwrites binned)
  k_prep<<<512, 256, 0, stream>>>(Wxs, Wxn, Whs, Whn, bprep);
  k_prepw<<<8, 256, 0, stream>>>(Wout, wprep);
  k_convxall<<<(T_STEPS * NN * 8 + 255) / 256, 256, 0, stream>>>(x, XQ);
  k_inith<<<NN * 8 / 256, 256, 0, stream>>>(h0, c0, H0bf, L1bf, HQ, C16);
  k_aggx<<<(NN + 3) / 4, 256, 0, stream>>>(XQ, row_ptr, csr, deg_inv, AGGXq);
  k_agg_pair<<<(NN + 3) / 4, 256, 0, stream>>>(HQ, row_ptr, csr, deg_inv, AGGH0, AGGH1);

  for (int t = 0; t < T_STEPS; ++t) {
    int wf = (t == T_STEPS - 1) ? 1 : 0;
    // layer 0: inp=x_t fp32, xagg=AGGXq[t] fp8, h=H0bf (in-place), hagg=AGGH0
    k_gates0<<<(NN + 63) / 64, 256, 0, stream>>>(
        x + (size_t)t * NN * HD, AGGXq + (size_t)t * NN * 64,
        H0bf, AGGH0, HQ, C16, hstate, cstate, bprep, wc, bias, NN, wf);
    // one pair gather: agg(h_l0 new) -> AGGH0, agg(h_l1 old) -> AGGH1
    k_agg_pair<<<(NN + 3) / 4, 256, 0, stream>>>(HQ, row_ptr, csr, deg_inv, AGGH0, AGGH1);
    // layer 1 (+ out-proj): inp=H0bf, xagg=AGGH0, h=L1bf (in-place), hagg=AGGH1
    k_gates1<<<(NN + 63) / 64, 256, 0, stream>>>(
        H0bf, AGGH0, AGGH1, L1bf, HQ, C16 + (size_t)NN * 64,
        hstate + (size_t)NN * HD, cstate + (size_t)NN * HD,
        bprep + 65536, wc + 192, bias + 256,
        wprep, bout, outs + (size_t)t * NN * OD, NN, wf);
  }
}

// Round 9
// 2884.704 us; speedup vs baseline: 1.2250x; 1.0345x over previous
//
#include <hip/hip_runtime.h>

#define T_STEPS 12
#define NN 100000
#define EE 3200000
#define HD 64
#define OD 32
#define NBK 391  // (NN+255)/256 buckets of 256 nodes

typedef __attribute__((ext_vector_type(8))) short short8;
typedef __attribute__((ext_vector_type(4))) float f32x4;
typedef __attribute__((ext_vector_type(2))) float f32x2;
typedef unsigned short u16;
typedef unsigned char u8;

__device__ __forceinline__ u16 f2b(float x) {
  union { float f; unsigned u; } v; v.f = x;
  unsigned r = v.u + 0x7FFFu + ((v.u >> 16) & 1u);
  return (u16)(r >> 16);
}
__device__ __forceinline__ u16 f2h(float x) {
  union { _Float16 h; u16 s; } u; u.h = (_Float16)x; return u.s;
}
__device__ __forceinline__ float h2f(u16 s) {
  union { u16 s; _Float16 h; } u; u.s = s; return (float)u.h;
}
__device__ __forceinline__ float sigm(float x) {
  x = fminf(fmaxf(x, -30.f), 30.f);
  return 1.0f / (1.0f + __expf(-x));
}
__device__ __forceinline__ float tanh_f(float x) {
  x = fminf(fmaxf(x, -15.f), 15.f);
  float e = __expf(2.0f * x);
  return (e - 1.0f) / (e + 1.0f);
}

// fp8 e4m3 (OCP) helpers via gfx950 HW converts
__device__ __forceinline__ uint2 pack8_fp8(const float* f) {
  unsigned lo = 0, hi = 0;
  lo = __builtin_amdgcn_cvt_pk_fp8_f32(f[0], f[1], lo, false);
  lo = __builtin_amdgcn_cvt_pk_fp8_f32(f[2], f[3], lo, true);
  hi = __builtin_amdgcn_cvt_pk_fp8_f32(f[4], f[5], hi, false);
  hi = __builtin_amdgcn_cvt_pk_fp8_f32(f[6], f[7], hi, true);
  return make_uint2(lo, hi);
}
__device__ __forceinline__ u8 f2q(float x) {
  return (u8)(__builtin_amdgcn_cvt_pk_fp8_f32(x, 0.f, 0u, false) & 0xFFu);
}
__device__ __forceinline__ void acc8_fp8(uint2 v, float* a) {
  f32x2 p0 = __builtin_amdgcn_cvt_pk_f32_fp8(v.x, false);
  f32x2 p1 = __builtin_amdgcn_cvt_pk_f32_fp8(v.x, true);
  f32x2 p2 = __builtin_amdgcn_cvt_pk_f32_fp8(v.y, false);
  f32x2 p3 = __builtin_amdgcn_cvt_pk_f32_fp8(v.y, true);
  a[0] += p0[0]; a[1] += p0[1]; a[2] += p1[0]; a[3] += p1[1];
  a[4] += p2[0]; a[5] += p2[1]; a[6] += p3[0]; a[7] += p3[1];
}
__device__ __forceinline__ void dec16_acc2(uint4 q, f32x2* a) {
  a[0] += __builtin_amdgcn_cvt_pk_f32_fp8(q.x, false);
  a[1] += __builtin_amdgcn_cvt_pk_f32_fp8(q.x, true);
  a[2] += __builtin_amdgcn_cvt_pk_f32_fp8(q.y, false);
  a[3] += __builtin_amdgcn_cvt_pk_f32_fp8(q.y, true);
  a[4] += __builtin_amdgcn_cvt_pk_f32_fp8(q.z, false);
  a[5] += __builtin_amdgcn_cvt_pk_f32_fp8(q.z, true);
  a[6] += __builtin_amdgcn_cvt_pk_f32_fp8(q.w, false);
  a[7] += __builtin_amdgcn_cvt_pk_f32_fp8(q.w, true);
}
__device__ __forceinline__ short8 s8_from_fp8(uint2 q) {
  f32x2 p0 = __builtin_amdgcn_cvt_pk_f32_fp8(q.x, false);
  f32x2 p1 = __builtin_amdgcn_cvt_pk_f32_fp8(q.x, true);
  f32x2 p2 = __builtin_amdgcn_cvt_pk_f32_fp8(q.y, false);
  f32x2 p3 = __builtin_amdgcn_cvt_pk_f32_fp8(q.y, true);
  short8 o;
  o[0] = (short)f2b(p0[0]); o[1] = (short)f2b(p0[1]);
  o[2] = (short)f2b(p1[0]); o[3] = (short)f2b(p1[1]);
  o[4] = (short)f2b(p2[0]); o[5] = (short)f2b(p2[1]);
  o[6] = (short)f2b(p3[0]); o[7] = (short)f2b(p3[1]);
  return o;
}
__device__ __forceinline__ short8 s8_from_f32(float4 a, float4 b) {
  short8 o;
  o[0] = (short)f2b(a.x); o[1] = (short)f2b(a.y);
  o[2] = (short)f2b(a.z); o[3] = (short)f2b(a.w);
  o[4] = (short)f2b(b.x); o[5] = (short)f2b(b.y);
  o[6] = (short)f2b(b.z); o[7] = (short)f2b(b.w);
  return o;
}

// ================= bucketed CSR build =================
__global__ __launch_bounds__(256) void k_bhist(const int* __restrict__ dst,
                                               int* __restrict__ bcnt, int E) {
  __shared__ int h[NBK];
  for (int i = threadIdx.x; i < NBK; i += 256) h[i] = 0;
  __syncthreads();
  int base = blockIdx.x * 4096;
#pragma unroll
  for (int i = 0; i < 16; ++i) {
    int e = base + i * 256 + threadIdx.x;
    if (e < E) atomicAdd(&h[dst[e] >> 8], 1);
  }
  __syncthreads();
  for (int i = threadIdx.x; i < NBK; i += 256)
    if (h[i]) atomicAdd(&bcnt[i], h[i]);
}

__global__ __launch_bounds__(512) void k_bscan(const int* __restrict__ bcnt,
                                               int* __restrict__ bbase,
                                               int* __restrict__ bcur) {
  __shared__ int buf[512];
  int tid = threadIdx.x;
  int v = (tid < NBK) ? bcnt[tid] : 0;
  buf[tid] = v;
  __syncthreads();
  for (int off = 1; off < 512; off <<= 1) {
    int t = (tid >= off) ? buf[tid - off] : 0;
    __syncthreads();
    buf[tid] += t;
    __syncthreads();
  }
  if (tid < NBK) {
    int e = buf[tid] - v;
    bbase[tid] = e;
    bcur[tid] = e;
  }
}

__global__ __launch_bounds__(256) void k_bscatter(const int* __restrict__ src,
                                                  const int* __restrict__ dst,
                                                  int* __restrict__ bcur,
                                                  uint2* __restrict__ binned, int E) {
  __shared__ int h[NBK];
  __shared__ int base[NBK];
  __shared__ int cur[NBK];
  for (int i = threadIdx.x; i < NBK; i += 256) { h[i] = 0; cur[i] = 0; }
  __syncthreads();
  int b0 = blockIdx.x * 4096;
  int d[16], s[16];
#pragma unroll
  for (int i = 0; i < 16; ++i) {
    int e = b0 + i * 256 + threadIdx.x;
    if (e < E) {
      d[i] = dst[e];
      s[i] = src[e];
      atomicAdd(&h[d[i] >> 8], 1);
    } else d[i] = -1;
  }
  __syncthreads();
  for (int i = threadIdx.x; i < NBK; i += 256)
    if (h[i]) base[i] = atomicAdd(&bcur[i], h[i]);
  __syncthreads();
#pragma unroll
  for (int i = 0; i < 16; ++i) {
    if (d[i] >= 0) {
      int bk = d[i] >> 8;
      int r = atomicAdd(&cur[bk], 1);
      binned[base[bk] + r] = make_uint2((unsigned)s[i], (unsigned)d[i]);
    }
  }
}

// per-bucket LDS counting sort: builds csr + row_ptr + deg_inv in one pass
__global__ __launch_bounds__(256) void k_bsort(const uint2* __restrict__ binned,
                                               const int* __restrict__ bbase,
                                               const int* __restrict__ bcnt,
                                               int* __restrict__ csr,
                                               int* __restrict__ row_ptr,
                                               float* __restrict__ deg_inv, int n) {
  __shared__ int cnt[256];
  __shared__ int buf[256];
  __shared__ int cur[256];
  int b = blockIdx.x, tid = threadIdx.x;
  int ebase = bbase[b];
  int ecnt = bcnt[b];
  cnt[tid] = 0;
  __syncthreads();
  for (int i = tid; i < ecnt; i += 256)
    atomicAdd(&cnt[binned[ebase + i].y & 255], 1);
  __syncthreads();
  int v = cnt[tid];
  buf[tid] = v;
  __syncthreads();
  for (int off = 1; off < 256; off <<= 1) {
    int t = (tid >= off) ? buf[tid - off] : 0;
    __syncthreads();
    buf[tid] += t;
    __syncthreads();
  }
  int excl = buf[tid] - v;
  int node = b * 256 + tid;
  if (node < n) {
    row_ptr[node] = ebase + excl;
    deg_inv[node] = v ? (1.0f / (float)v) : 0.0f;
  }
  if (b == NBK - 1 && tid == 0) row_ptr[n] = ebase + ecnt;
  cur[tid] = excl;
  __syncthreads();
  for (int i = tid; i < ecnt; i += 256) {
    uint2 pr = binned[ebase + i];
    int pos = atomicAdd(&cur[pr.y & 255], 1);
    csr[ebase + pos] = (int)pr.x;
  }
}

// ---------------- weight prep: fragment-ordered bf16 B ----------------
__global__ __launch_bounds__(256) void k_prep(const float* __restrict__ Wxs,
                                              const float* __restrict__ Wxn,
                                              const float* __restrict__ Whs,
                                              const float* __restrict__ Whn,
                                              u16* __restrict__ bprep) {
  int idx = blockIdx.x * 256 + threadIdx.x;  // 0..131071
  int l = idx >> 16;
  int kb = (idx >> 13) & 7;
  int fi = (idx >> 9) & 15;
  int ln = (idx >> 3) & 63;
  int j = idx & 7;
  int fc = kb * 32 + ((ln >> 4) << 3) + j;
  int g = fi & 3;
  int kk = ((fi >> 2) << 4) + (ln & 15);
  int t = fc >> 6, f = fc & 63;
  const float* tabs[4] = {Wxs, Wxn, Whs, Whn};
  bprep[idx] = f2b(tabs[t][((size_t)(l * 4 + g) * 64 + f) * 64 + kk]);
}

__global__ __launch_bounds__(256) void k_prepw(const float* __restrict__ Wout,
                                               u16* __restrict__ wp) {
  int idx = blockIdx.x * 256 + threadIdx.x;  // 0..2047
  int kb = idx >> 10;
  int fi = (idx >> 9) & 1;
  int ln = (idx >> 3) & 63;
  int j = idx & 7;
  int k = kb * 32 + ((ln >> 4) << 3) + j;
  int o = fi * 16 + (ln & 15);
  wp[idx] = f2b(Wout[k * 32 + o]);
}

// ---------------- batch x -> transposed fp8 XQ[N][T*64] ----------------
__global__ __launch_bounds__(256) void k_convxall(const float* __restrict__ x,
                                                  u8* __restrict__ XQ) {
  int tid = blockIdx.x * 256 + threadIdx.x;  // (t*NN + n)*8 + j
  int j = tid & 7;
  int tn = tid >> 3;
  int n = tn % NN;
  int t = tn / NN;
  const float* rp = x + (size_t)tn * 64 + j * 8;
  float4 v0 = *reinterpret_cast<const float4*>(rp);
  float4 v1 = *reinterpret_cast<const float4*>(rp + 4);
  float f[8] = {v0.x, v0.y, v0.z, v0.w, v1.x, v1.y, v1.z, v1.w};
  *reinterpret_cast<uint2*>(XQ + (size_t)n * 768 + t * 64 + j * 8) = pack8_fp8(f);
}

// -------- init h (bf16 tables + fp8 HQ pair) and c (fp16) --------
__global__ __launch_bounds__(256) void k_inith(const float* __restrict__ h0,
                                               const float* __restrict__ c0,
                                               u16* __restrict__ H0bf,
                                               u16* __restrict__ L1bf,
                                               u8* __restrict__ HQ,
                                               u16* __restrict__ C16) {
  int idx = blockIdx.x * 256 + threadIdx.x;  // N*8
  int n = idx >> 3, j = idx & 7;
#pragma unroll
  for (int L = 0; L < 2; ++L) {
    const float* rp = h0 + (size_t)L * NN * 64 + (size_t)n * 64 + j * 8;
    float4 v0 = *reinterpret_cast<const float4*>(rp);
    float4 v1 = *reinterpret_cast<const float4*>(rp + 4);
    float f[8] = {v0.x, v0.y, v0.z, v0.w, v1.x, v1.y, v1.z, v1.w};
    short8 o;
#pragma unroll
    for (int i = 0; i < 8; ++i) o[i] = (short)f2b(f[i]);
    if (L == 0)
      *reinterpret_cast<short8*>(H0bf + (size_t)n * 64 + j * 8) = o;
    else
      *reinterpret_cast<short8*>(L1bf + (size_t)n * 64 + j * 8) = o;
    *reinterpret_cast<uint2*>(HQ + (size_t)n * 128 + L * 64 + j * 8) = pack8_fp8(f);
    const float* cp = c0 + (size_t)L * NN * 64 + (size_t)n * 64 + j * 8;
    float4 c0v = *reinterpret_cast<const float4*>(cp);
    float4 c1v = *reinterpret_cast<const float4*>(cp + 4);
    float cf[8] = {c0v.x, c0v.y, c0v.z, c0v.w, c1v.x, c1v.y, c1v.z, c1v.w};
    short8 oc;
#pragma unroll
    for (int i = 0; i < 8; ++i) oc[i] = (short)f2h(cf[i]);
    *reinterpret_cast<short8*>(C16 + (size_t)L * NN * 64 + (size_t)n * 64 + j * 8) = oc;
  }
}

// ------- batched x aggregation: blockIdx.y = 256-B time-slice (4 steps) -----
// 4 edge slots (g) x 16 lanes (m) x 16B; depth-4 main, depth-2/1 tail.
__global__ __launch_bounds__(256) void k_aggx(const u8* __restrict__ XQ,
                                              const int* __restrict__ row_ptr,
                                              const int* __restrict__ csr,
                                              const float* __restrict__ deg_inv,
                                              u8* __restrict__ AGGXq) {
  int node = blockIdx.x * 4 + (threadIdx.x >> 6);
  int p = blockIdx.y;  // 0..2
  int lane = threadIdx.x & 63;
  int g = lane >> 4, m = lane & 15;
  int start = row_ptr[node], end = row_ptr[node + 1];
  const size_t poff = (size_t)p * 256 + m * 16;
  f32x2 a[8];
#pragma unroll
  for (int i = 0; i < 8; ++i) a[i] = (f32x2){0.f, 0.f};
  int e = start + g;
  for (; e + 12 < end; e += 16) {
    int s0 = csr[e], s1 = csr[e + 4], s2 = csr[e + 8], s3 = csr[e + 12];
    uint4 q0 = *reinterpret_cast<const uint4*>(XQ + (size_t)s0 * 768 + poff);
    uint4 q1 = *reinterpret_cast<const uint4*>(XQ + (size_t)s1 * 768 + poff);
    uint4 q2 = *reinterpret_cast<const uint4*>(XQ + (size_t)s2 * 768 + poff);
    uint4 q3 = *reinterpret_cast<const uint4*>(XQ + (size_t)s3 * 768 + poff);
    dec16_acc2(q0, a); dec16_acc2(q1, a); dec16_acc2(q2, a); dec16_acc2(q3, a);
  }
  if (e + 4 < end) {
    int s0 = csr[e], s1 = csr[e + 4];
    uint4 q0 = *reinterpret_cast<const uint4*>(XQ + (size_t)s0 * 768 + poff);
    uint4 q1 = *reinterpret_cast<const uint4*>(XQ + (size_t)s1 * 768 + poff);
    dec16_acc2(q0, a); dec16_acc2(q1, a);
    e += 8;
  }
  if (e < end) {
    int s0 = csr[e];
    uint4 q0 = *reinterpret_cast<const uint4*>(XQ + (size_t)s0 * 768 + poff);
    dec16_acc2(q0, a);
  }
#pragma unroll
  for (int off = 16; off < 64; off <<= 1)
#pragma unroll
    for (int i = 0; i < 8; ++i) {
      a[i][0] += __shfl_xor(a[i][0], off);
      a[i][1] += __shfl_xor(a[i][1], off);
    }
  if (g == 0) {
    float sc = deg_inv[node];
    float f[16];
#pragma unroll
    for (int i = 0; i < 8; ++i) {
      f[i * 2] = a[i][0] * sc;
      f[i * 2 + 1] = a[i][1] * sc;
    }
    uint4 o;
    unsigned w;
    w = 0; w = __builtin_amdgcn_cvt_pk_fp8_f32(f[0], f[1], w, false);
    w = __builtin_amdgcn_cvt_pk_fp8_f32(f[2], f[3], w, true); o.x = w;
    w = 0; w = __builtin_amdgcn_cvt_pk_fp8_f32(f[4], f[5], w, false);
    w = __builtin_amdgcn_cvt_pk_fp8_f32(f[6], f[7], w, true); o.y = w;
    w = 0; w = __builtin_amdgcn_cvt_pk_fp8_f32(f[8], f[9], w, false);
    w = __builtin_amdgcn_cvt_pk_fp8_f32(f[10], f[11], w, true); o.z = w;
    w = 0; w = __builtin_amdgcn_cvt_pk_fp8_f32(f[12], f[13], w, false);
    w = __builtin_amdgcn_cvt_pk_fp8_f32(f[14], f[15], w, true); o.w = w;
    int t = p * 4 + (m >> 2);
    *reinterpret_cast<uint4*>(AGGXq + ((size_t)t * NN + node) * 64 + (m & 3) * 16) = o;
  }
}

// ------- dual mean aggregation over HQ [N][128] fp8 -> two [N][64] bf16 -----
__global__ __launch_bounds__(256) void k_agg_pair(const u8* __restrict__ Q,
                                                  const int* __restrict__ row_ptr,
                                                  const int* __restrict__ csr,
                                                  const float* __restrict__ deg_inv,
                                                  u16* __restrict__ out0,
                                                  u16* __restrict__ out1) {
  int node = blockIdx.x * 4 + (threadIdx.x >> 6);
  int lane = threadIdx.x & 63;
  int g = lane >> 4, m = lane & 15;
  int start = row_ptr[node], end = row_ptr[node + 1];
  float a[8] = {0, 0, 0, 0, 0, 0, 0, 0};
  int e = start + g;
  for (; e + 12 < end; e += 16) {
    int s0 = csr[e], s1 = csr[e + 4], s2 = csr[e + 8], s3 = csr[e + 12];
    uint2 v0 = *reinterpret_cast<const uint2*>(Q + (size_t)s0 * 128 + m * 8);
    uint2 v1 = *reinterpret_cast<const uint2*>(Q + (size_t)s1 * 128 + m * 8);
    uint2 v2 = *reinterpret_cast<const uint2*>(Q + (size_t)s2 * 128 + m * 8);
    uint2 v3 = *reinterpret_cast<const uint2*>(Q + (size_t)s3 * 128 + m * 8);
    acc8_fp8(v0, a); acc8_fp8(v1, a); acc8_fp8(v2, a); acc8_fp8(v3, a);
  }
  if (e + 4 < end) {
    int s0 = csr[e], s1 = csr[e + 4];
    uint2 v0 = *reinterpret_cast<const uint2*>(Q + (size_t)s0 * 128 + m * 8);
    uint2 v1 = *reinterpret_cast<const uint2*>(Q + (size_t)s1 * 128 + m * 8);
    acc8_fp8(v0, a); acc8_fp8(v1, a);
    e += 8;
  }
  if (e < end) {
    int s0 = csr[e];
    uint2 v0 = *reinterpret_cast<const uint2*>(Q + (size_t)s0 * 128 + m * 8);
    acc8_fp8(v0, a);
  }
#pragma unroll
  for (int off = 16; off < 64; off <<= 1) {
#pragma unroll
    for (int i = 0; i < 8; ++i) a[i] += __shfl_xor(a[i], off);
  }
  if (g == 0) {
    float sc = deg_inv[node];
    short8 o;
#pragma unroll
    for (int i = 0; i < 8; ++i) o[i] = (short)f2b(a[i] * sc);
    if (m < 8)
      *reinterpret_cast<short8*>(out0 + (size_t)node * 64 + m * 8) = o;
    else
      *reinterpret_cast<short8*>(out1 + (size_t)node * 64 + (m - 8) * 8) = o;
  }
}

// ---------------- layer-0 gates ----------------
__global__ __launch_bounds__(256, 2) void k_gates0(
    const float* __restrict__ xin, const u8* __restrict__ aggxq,
    u16* __restrict__ h0bf, const u16* __restrict__ aggh0,
    u8* __restrict__ hq, u16* __restrict__ c16,
    float* __restrict__ hf32, float* __restrict__ cf32,
    const u16* __restrict__ bprepl,
    const float* __restrict__ wcl, const float* __restrict__ biasl,
    int n_nodes, int wf) {
  const int tid = threadIdx.x;
  const int lane = tid & 63;
  const int w = tid >> 6;
  const int nb = blockIdx.x * 64;
  const int cl = lane & 15;
  const int kg = lane >> 4;

  short8 breg[8][4];
#pragma unroll
  for (int kb = 0; kb < 8; ++kb)
#pragma unroll
    for (int fl = 0; fl < 4; ++fl)
      breg[kb][fl] = *reinterpret_cast<const short8*>(
          bprepl + (kb << 13) + (((w << 2) + fl) << 9) + (lane << 3));

  int gnc[4];
#pragma unroll
  for (int rg = 0; rg < 4; ++rg) {
    int g = nb + rg * 16 + cl;
    gnc[rg] = (g < n_nodes) ? g : (n_nodes - 1);
  }

  f32x4 acc[4][4];
  f32x4 z4 = {0.f, 0.f, 0.f, 0.f};
#pragma unroll
  for (int a = 0; a < 4; ++a)
#pragma unroll
    for (int b = 0; b < 4; ++b) acc[a][b] = z4;

  const int koff = kg << 3;
#pragma unroll
  for (int kb = 0; kb < 8; ++kb) {
    const int idx = ((kb & 1) << 5) + koff;
#pragma unroll
    for (int rg = 0; rg < 4; ++rg) {
      short8 a;
      if (kb < 2) {
        const float* rp = xin + (size_t)gnc[rg] * 64 + idx;
        a = s8_from_f32(*reinterpret_cast<const float4*>(rp),
                        *reinterpret_cast<const float4*>(rp + 4));
      } else if (kb < 4) {
        a = s8_from_fp8(*reinterpret_cast<const uint2*>(aggxq + (size_t)gnc[rg] * 64 + idx));
      } else if (kb < 6) {
        a = *reinterpret_cast<const short8*>(h0bf + (size_t)gnc[rg] * 64 + idx);
      } else {
        a = *reinterpret_cast<const short8*>(aggh0 + (size_t)gnc[rg] * 64 + idx);
      }
      acc[rg][0] = __builtin_amdgcn_mfma_f32_16x16x32_bf16(a, breg[kb][0], acc[rg][0], 0, 0, 0);
      acc[rg][1] = __builtin_amdgcn_mfma_f32_16x16x32_bf16(a, breg[kb][1], acc[rg][1], 0, 0, 0);
      acc[rg][2] = __builtin_amdgcn_mfma_f32_16x16x32_bf16(a, breg[kb][2], acc[rg][2], 0, 0, 0);
      acc[rg][3] = __builtin_amdgcn_mfma_f32_16x16x32_bf16(a, breg[kb][3], acc[rg][3], 0, 0, 0);
    }
  }
  __syncthreads();  // all h0bf A-reads complete before in-place writes

  const int k = (w << 4) + cl;
  const float wci = wcl[k], wcf = wcl[64 + k], wco = wcl[128 + k];
  const float bi = biasl[k], bfg = biasl[64 + k], bc = biasl[128 + k], bo = biasl[192 + k];
#pragma unroll
  for (int rg = 0; rg < 4; ++rg) {
#pragma unroll
    for (int r = 0; r < 4; ++r) {
      int n = nb + rg * 16 + kg * 4 + r;
      if (n < n_nodes) {
        size_t off = (size_t)n * 64 + k;
        float c_old = h2f(c16[off]);
        float ig = sigm(acc[rg][0][r] + wci * c_old + bi);
        float fg = sigm(acc[rg][1][r] + wcf * c_old + bfg);
        float ct = tanh_f(acc[rg][2][r] + bc);
        float nc = fg * c_old + ig * ct;
        float og = sigm(acc[rg][3][r] + wco * nc + bo);
        float nh = og * tanh_f(nc);
        c16[off] = f2h(nc);
        h0bf[off] = f2b(nh);
        hq[(size_t)n * 128 + k] = f2q(nh);
        if (wf) { hf32[off] = nh; cf32[off] = nc; }
      }
    }
  }
}

// ---------------- layer-1 gates + fused out-proj ----------------
__global__ __launch_bounds__(256, 2) void k_gates1(
    const u16* __restrict__ h0bf, const u16* __restrict__ aggh0,
    const u16* __restrict__ aggh1,
    u16* __restrict__ l1bf, u8* __restrict__ hq, u16* __restrict__ c16,
    float* __restrict__ hf32, float* __restrict__ cf32,
    const u16* __restrict__ bprepl,
    const float* __restrict__ wcl, const float* __restrict__ biasl,
    const u16* __restrict__ wproj, const float* __restrict__ boutp,
    float* __restrict__ outp, int n_nodes, int wf) {
  __shared__ u16 Hsm[64 * 64];  // 8 KB
  const int tid = threadIdx.x;
  const int lane = tid & 63;
  const int w = tid >> 6;
  const int nb = blockIdx.x * 64;
  const int cl = lane & 15;
  const int kg = lane >> 4;

  short8 breg[8][4];
#pragma unroll
  for (int kb = 0; kb < 8; ++kb)
#pragma unroll
    for (int fl = 0; fl < 4; ++fl)
      breg[kb][fl] = *reinterpret_cast<const short8*>(
          bprepl + (kb << 13) + (((w << 2) + fl) << 9) + (lane << 3));

  int gnc[4];
#pragma unroll
  for (int rg = 0; rg < 4; ++rg) {
    int g = nb + rg * 16 + cl;
    gnc[rg] = (g < n_nodes) ? g : (n_nodes - 1);
  }

  f32x4 acc[4][4];
  f32x4 z4 = {0.f, 0.f, 0.f, 0.f};
#pragma unroll
  for (int a = 0; a < 4; ++a)
#pragma unroll
    for (int b = 0; b < 4; ++b) acc[a][b] = z4;

  const int koff = kg << 3;
#pragma unroll
  for (int kb = 0; kb < 8; ++kb) {
    const int idx = ((kb & 1) << 5) + koff;
#pragma unroll
    for (int rg = 0; rg < 4; ++rg) {
      short8 a;
      if (kb < 2) {
        a = *reinterpret_cast<const short8*>(h0bf + (size_t)gnc[rg] * 64 + idx);
      } else if (kb < 4) {
        a = *reinterpret_cast<const short8*>(aggh0 + (size_t)gnc[rg] * 64 + idx);
      } else if (kb < 6) {
        a = *reinterpret_cast<const short8*>(l1bf + (size_t)gnc[rg] * 64 + idx);
      } else {
        a = *reinterpret_cast<const short8*>(aggh1 + (size_t)gnc[rg] * 64 + idx);
      }
      acc[rg][0] = __builtin_amdgcn_mfma_f32_16x16x32_bf16(a, breg[kb][0], acc[rg][0], 0, 0, 0);
      acc[rg][1] = __builtin_amdgcn_mfma_f32_16x16x32_bf16(a, breg[kb][1], acc[rg][1], 0, 0, 0);
      acc[rg][2] = __builtin_amdgcn_mfma_f32_16x16x32_bf16(a, breg[kb][2], acc[rg][2], 0, 0, 0);
      acc[rg][3] = __builtin_amdgcn_mfma_f32_16x16x32_bf16(a, breg[kb][3], acc[rg][3], 0, 0, 0);
    }
  }
  __syncthreads();  // all l1bf A-reads complete before in-place writes

  const int k = (w << 4) + cl;
  const float wci = wcl[k], wcf = wcl[64 + k], wco = wcl[128 + k];
  const float bi = biasl[k], bfg = biasl[64 + k], bc = biasl[128 + k], bo = biasl[192 + k];
#pragma unroll
  for (int rg = 0; rg < 4; ++rg) {
#pragma unroll
    for (int r = 0; r < 4; ++r) {
      int n = nb + rg * 16 + kg * 4 + r;
      if (n < n_nodes) {
        size_t off = (size_t)n * 64 + k;
        float c_old = h2f(c16[off]);
        float ig = sigm(acc[rg][0][r] + wci * c_old + bi);
        float fg = sigm(acc[rg][1][r] + wcf * c_old + bfg);
        float ct = tanh_f(acc[rg][2][r] + bc);
        float nc = fg * c_old + ig * ct;
        float og = sigm(acc[rg][3][r] + wco * nc + bo);
        float nh = og * tanh_f(nc);
        c16[off] = f2h(nc);
        u16 hb = f2b(nh);
        l1bf[off] = hb;
        hq[(size_t)n * 128 + 64 + k] = f2q(nh);
        Hsm[(rg * 16 + kg * 4 + r) * 64 + k] = hb;
        if (wf) { hf32[off] = nh; cf32[off] = nc; }
      }
    }
  }

  __syncthreads();
  short8 bw[2][2];
#pragma unroll
  for (int kb = 0; kb < 2; ++kb)
#pragma unroll
    for (int fi = 0; fi < 2; ++fi)
      bw[kb][fi] = *reinterpret_cast<const short8*>(wproj + (((kb * 2 + fi) * 64 + lane) << 3));
  short8 a0 = *reinterpret_cast<const short8*>(&Hsm[(w * 16 + cl) * 64 + kg * 8]);
  short8 a1 = *reinterpret_cast<const short8*>(&Hsm[(w * 16 + cl) * 64 + 32 + kg * 8]);
  f32x4 p0 = z4, p1 = z4;
  p0 = __builtin_amdgcn_mfma_f32_16x16x32_bf16(a0, bw[0][0], p0, 0, 0, 0);
  p0 = __builtin_amdgcn_mfma_f32_16x16x32_bf16(a1, bw[1][0], p0, 0, 0, 0);
  p1 = __builtin_amdgcn_mfma_f32_16x16x32_bf16(a0, bw[0][1], p1, 0, 0, 0);
  p1 = __builtin_amdgcn_mfma_f32_16x16x32_bf16(a1, bw[1][1], p1, 0, 0, 0);
  const float bo0 = boutp[cl], bo1 = boutp[16 + cl];
#pragma unroll
  for (int r = 0; r < 4; ++r) {
    int n = nb + w * 16 + kg * 4 + r;
    if (n < n_nodes) {
      outp[(size_t)n * OD + cl] = p0[r] + bo0;
      outp[(size_t)n * OD + 16 + cl] = p1[r] + bo1;
    }
  }
}

extern "C" void kernel_launch(void* const* d_in, const int* in_sizes, int n_in,
                              void* d_out, int out_size, void* d_ws, size_t ws_size,
                              hipStream_t stream) {
  const float* x = (const float*)d_in[0];
  const float* h0 = (const float*)d_in[1];
  const float* c0 = (const float*)d_in[2];
  const float* Wxs = (const float*)d_in[3];
  const float* Wxn = (const float*)d_in[4];
  const float* Whs = (const float*)d_in[5];
  const float* Whn = (const float*)d_in[6];
  const float* wc = (const float*)d_in[7];
  const float* bias = (const float*)d_in[8];
  const float* Wout = (const float*)d_in[9];
  const float* bout = (const float*)d_in[10];
  const int* src = (const int*)d_in[11];
  const int* dst = (const int*)d_in[12];

  float* out = (float*)d_out;
  float* outs = out;                                   // [T][N][O]
  float* hstate = out + (size_t)T_STEPS * NN * OD;     // [2][N][64] fp32 (final only)
  float* cstate = hstate + (size_t)2 * NN * HD;        // [2][N][64] fp32 (final only)

  char* p = (char*)d_ws;
  auto alloc = [&](size_t bytes) {
    char* r = p;
    p += (bytes + 255) & ~(size_t)255;
    return r;
  };
  int* csr = (int*)alloc((size_t)EE * 4);
  u8* XQ = (u8*)alloc((size_t)NN * 768);        // x fp8, node-major [N][T*64]
  uint2* binned = (uint2*)XQ;                   // alias: binned dead before XQ written
  u8* AGGXq = (u8*)alloc((size_t)T_STEPS * NN * 64);  // [T][N][64] fp8
  int* row_ptr = (int*)alloc((size_t)(NN + 1) * 4);
  int* bcnt = (int*)alloc(NBK * 4);
  int* bbase = (int*)alloc(NBK * 4);
  int* bcur = (int*)alloc(NBK * 4);
  float* deg_inv = (float*)alloc((size_t)NN * 4);
  u16* H0bf = (u16*)alloc((size_t)NN * 64 * 2);   // h_l0 bf16
  u16* L1bf = (u16*)alloc((size_t)NN * 64 * 2);   // h_l1 bf16
  u8* HQ = (u8*)alloc((size_t)NN * 128);          // [h_l0 | h_l1] fp8 pair
  u16* AGGH0 = (u16*)alloc((size_t)NN * 64 * 2);  // agg(h_l0) bf16
  u16* AGGH1 = (u16*)alloc((size_t)NN * 64 * 2);  // agg(h_l1) bf16
  u16* C16 = (u16*)alloc((size_t)2 * NN * 64 * 2);  // live c fp16 [2][N][64]
  u16* bprep = (u16*)alloc((size_t)2 * 65536 * 2);
  u16* wprep = (u16*)alloc((size_t)2048 * 2);

  const int nchunk = (EE + 4095) / 4096;  // 782

  // prologue: bucketed CSR build (hist -> scan -> bin-scatter -> LDS sort)
  hipMemsetAsync(bcnt, 0, (size_t)NBK * 4, stream);
  k_bhist<<<nchunk, 256, 0, stream>>>(dst, bcnt, EE);
  k_bscan<<<1, 512, 0, stream>>>(bcnt, bbase, bcur);
  k_bscatter<<<nchunk, 256, 0, stream>>>(src, dst, bcur, binned, EE);
  k_bsort<<<NBK, 256, 0, stream>>>(binned, bbase, bcnt, csr, row_ptr, deg_inv, NN);
  // weight prep + state init + batched x processing (XQ overwrites binned)
  k_prep<<<512, 256, 0, stream>>>(Wxs, Wxn, Whs, Whn, bprep);
  k_prepw<<<8, 256, 0, stream>>>(Wout, wprep);
  k_convxall<<<(T_STEPS * NN * 8 + 255) / 256, 256, 0, stream>>>(x, XQ);
  k_inith<<<NN * 8 / 256, 256, 0, stream>>>(h0, c0, H0bf, L1bf, HQ, C16);
  {
    dim3 g((NN + 3) / 4, 3);
    k_aggx<<<g, 256, 0, stream>>>(XQ, row_ptr, csr, deg_inv, AGGXq);
  }
  k_agg_pair<<<(NN + 3) / 4, 256, 0, stream>>>(HQ, row_ptr, csr, deg_inv, AGGH0, AGGH1);

  for (int t = 0; t < T_STEPS; ++t) {
    int wf = (t == T_STEPS - 1) ? 1 : 0;
    // layer 0: inp=x_t fp32, xagg=AGGXq[t] fp8, h=H0bf (in-place), hagg=AGGH0
    k_gates0<<<(NN + 63) / 64, 256, 0, stream>>>(
        x + (size_t)t * NN * HD, AGGXq + (size_t)t * NN * 64,
        H0bf, AGGH0, HQ, C16, hstate, cstate, bprep, wc, bias, NN, wf);
    // one pair gather: agg(h_l0 new) -> AGGH0, agg(h_l1 old) -> AGGH1
    k_agg_pair<<<(NN + 3) / 4, 256, 0, stream>>>(HQ, row_ptr, csr, deg_inv, AGGH0, AGGH1);
    // layer 1 (+ out-proj): inp=H0bf, xagg=AGGH0, h=L1bf (in-place), hagg=AGGH1
    k_gates1<<<(NN + 63) / 64, 256, 0, stream>>>(
        H0bf, AGGH0, AGGH1, L1bf, HQ, C16 + (size_t)NN * 64,
        hstate + (size_t)NN * HD, cstate + (size_t)NN * HD,
        bprep + 65536, wc + 192, bias + 256,
        wprep, bout, outs + (size_t)t * NN * OD, NN, wf);
  }
}